// Round 18
// baseline (330.232 us; speedup 1.0000x reference)
//
#include <hip/hip_runtime.h>
#include <hip/hip_fp16.h>

#define H 64
#define BSHIFT 9
#define BUCKET 512
#define NBMAX 256
#define CHUNK 4096

__device__ __forceinline__ int bcasti(int x, int j) {
    return __builtin_amdgcn_readlane(x, j);
}
__device__ __forceinline__ float bcastf(float x, int j) {
    return __uint_as_float((unsigned)__builtin_amdgcn_readlane((int)__float_as_uint(x), j));
}

__device__ __forceinline__ float ldf(const float* p) { return *p; }
__device__ __forceinline__ float ldf(const __half* p) { return __half2float(*p); }

// v2all[b][k] = sum_j Wd_b[k][j] * ad_b[j]
__global__ void wvec3_kernel(const float* __restrict__ W_dst, const float* __restrict__ att_dst,
                             float* __restrict__ v2all) {
    int b = blockIdx.x;
    int k = threadIdx.x;
    const float* Wd = W_dst + (size_t)b * H * H;
    const float* ad = att_dst + (size_t)b * H;
    float s2 = 0.f;
    for (int j = 0; j < H; ++j) s2 += Wd[k * H + j] * ad[j];
    v2all[b * H + k] = s2;
}

// ---- proj device body: 16 rows/block, 4 rows/wave ----
template <typename T>
__device__ __forceinline__ void proj_body(float* __restrict__ Wl, int blk,
                                          const T* __restrict__ x, const float* __restrict__ W,
                                          const float* __restrict__ as_, const float* __restrict__ v2d,
                                          __half* __restrict__ hs, float* __restrict__ ssrc,
                                          float* __restrict__ sdst_out, int n) {
    int t = threadIdx.x;
    for (int i = t; i < H * H; i += 256) Wl[i] = W[i];
    __syncthreads();
    int lane = t & 63;
    int w = t >> 6;
    int row0 = blk * 16 + w * 4;
    if (row0 >= n) return;
    int rem = n - row0;
    float asl = as_[lane];
    const T* xp = x + (size_t)row0 * H + lane;
    float xr0 = ldf(xp);
    float xr1 = rem > 1 ? ldf(xp + H) : 0.f;
    float xr2 = rem > 2 ? ldf(xp + 2 * H) : 0.f;
    float xr3 = rem > 3 ? ldf(xp + 3 * H) : 0.f;
    float a0 = 0.f, a1 = 0.f, a2 = 0.f, a3 = 0.f;
#pragma unroll
    for (int k = 0; k < H; ++k) {
        float wv = Wl[k * H + lane];
        a0 = fmaf(bcastf(xr0, k), wv, a0);
        a1 = fmaf(bcastf(xr1, k), wv, a1);
        a2 = fmaf(bcastf(xr2, k), wv, a2);
        a3 = fmaf(bcastf(xr3, k), wv, a3);
    }
    __half* hp = hs + (size_t)row0 * H + lane;
    hp[0] = __float2half_rn(a0);
    if (rem > 1) hp[H] = __float2half_rn(a1);
    if (rem > 2) hp[2 * H] = __float2half_rn(a2);
    if (rem > 3) hp[3 * H] = __float2half_rn(a3);
    float p0 = a0 * asl, p1 = a1 * asl, p2 = a2 * asl, p3 = a3 * asl;
#pragma unroll
    for (int off = 32; off; off >>= 1) {
        p0 += __shfl_xor(p0, off); p1 += __shfl_xor(p1, off);
        p2 += __shfl_xor(p2, off); p3 += __shfl_xor(p3, off);
    }
    if (lane == 0) {
        ssrc[row0] = p0;
        if (rem > 1) ssrc[row0 + 1] = p1;
        if (rem > 2) ssrc[row0 + 2] = p2;
        if (rem > 3) ssrc[row0 + 3] = p3;
    }
    if (sdst_out) {
        float vl = v2d[lane];
        float q0 = xr0 * vl, q1 = xr1 * vl, q2 = xr2 * vl, q3 = xr3 * vl;
#pragma unroll
        for (int off = 32; off; off >>= 1) {
            q0 += __shfl_xor(q0, off); q1 += __shfl_xor(q1, off);
            q2 += __shfl_xor(q2, off); q3 += __shfl_xor(q3, off);
        }
        if (lane == 0) {
            sdst_out[row0] = q0;
            if (rem > 1) sdst_out[row0 + 1] = q1;
            if (rem > 2) sdst_out[row0 + 2] = q2;
            if (rem > 3) sdst_out[row0 + 3] = q3;
        }
    }
}

// ---- fused: part_hist || proj0 ----
__global__ void hist_proj_kernel(const int* __restrict__ dstA, const int* __restrict__ dstB,
                                 int* __restrict__ cntA, int* __restrict__ cntB,
                                 int ne, int nch, int nbA, int nbB,
                                 const float* __restrict__ x, const float* __restrict__ W,
                                 const float* __restrict__ as_, const float* __restrict__ v2d,
                                 __half* __restrict__ hs, float* __restrict__ ssrc,
                                 float* __restrict__ sdst_out, int n) {
    __shared__ float smem[H * H];
    int blk = blockIdx.x;
    if (blk < 2 * nch) {
        int* h = (int*)smem;
        bool second = blk >= nch;
        const int* dst = second ? dstB : dstA;
        int* cnt = second ? cntB : cntA;
        int nb = second ? nbB : nbA;
        int c = second ? blk - nch : blk;
        int beg = c * CHUNK, end = beg + CHUNK;
        if (end > ne) end = ne;
        int t = threadIdx.x;
        for (int i = t; i < NBMAX; i += 256) h[i] = 0;
        __syncthreads();
        for (int i = beg + t; i < end; i += 256) atomicAdd(&h[dst[i] >> BSHIFT], 1);
        __syncthreads();
        for (int b = t; b < nb; b += 256) cnt[(size_t)b * nch + c] = h[b];
        return;
    }
    proj_body<float>(smem, blk - 2 * nch, x, W, as_, v2d, hs, ssrc, sdst_out, n);
}

__global__ void scan_chunks(int* __restrict__ cntA, int* __restrict__ cntB,
                            int* __restrict__ totA, int* __restrict__ totB,
                            int nch, int nbA) {
    __shared__ int sm[512];
    int b = blockIdx.x;
    bool second = b >= nbA;
    int* cnt = second ? cntB : cntA;
    int* tot = second ? totB : totA;
    if (second) b -= nbA;
    int t = threadIdx.x;
    int v = t < nch ? cnt[(size_t)b * nch + t] : 0;
    sm[t] = v;
    __syncthreads();
    for (int off = 1; off < 512; off <<= 1) {
        int u = t >= off ? sm[t - off] : 0;
        __syncthreads();
        sm[t] += u;
        __syncthreads();
    }
    if (t < nch) cnt[(size_t)b * nch + t] = sm[t] - v;
    if (t == 511) tot[b] = sm[511];
}

__global__ void scan_buckets(const int* __restrict__ totA, const int* __restrict__ totB,
                             int* __restrict__ bstartA, int* __restrict__ bstartB,
                             int nbA, int nbB, int ne) {
    __shared__ int sm[256];
    const int* tot = blockIdx.x ? totB : totA;
    int* bstart = blockIdx.x ? bstartB : bstartA;
    int nb = blockIdx.x ? nbB : nbA;
    int t = threadIdx.x;
    int v = t < nb ? tot[t] : 0;
    sm[t] = v;
    __syncthreads();
    for (int off = 1; off < 256; off <<= 1) {
        int u = t >= off ? sm[t - off] : 0;
        __syncthreads();
        sm[t] += u;
        __syncthreads();
    }
    if (t < nb) bstart[t] = sm[t] - v;
    if (t == 0) bstart[nb] = ne;
}

// ---- fused: part_scatter || proj1 ----
__global__ void scatter_proj_kernel(const int* __restrict__ srcA, const int* __restrict__ dstA,
                                    const int* __restrict__ cntA, const int* __restrict__ bstartA,
                                    unsigned* __restrict__ tmpA,
                                    const int* __restrict__ srcB, const int* __restrict__ dstB,
                                    const int* __restrict__ cntB, const int* __restrict__ bstartB,
                                    unsigned* __restrict__ tmpB,
                                    int ne, int nch, int nbA, int nbB,
                                    const float* __restrict__ x, const float* __restrict__ W,
                                    const float* __restrict__ as_, const float* __restrict__ v2d,
                                    __half* __restrict__ hs, float* __restrict__ ssrc,
                                    float* __restrict__ sdst_out, int n) {
    __shared__ float smem[H * H];
    int blk = blockIdx.x;
    if (blk < 2 * nch) {
        int* cur = (int*)smem;
        bool second = blk >= nch;
        const int* src = second ? srcB : srcA;
        const int* dst = second ? dstB : dstA;
        const int* cnt = second ? cntB : cntA;
        const int* bstart = second ? bstartB : bstartA;
        unsigned* tmp = second ? tmpB : tmpA;
        int nb = second ? nbB : nbA;
        int c = second ? blk - nch : blk;
        int beg = c * CHUNK, end = beg + CHUNK;
        if (end > ne) end = ne;
        int t = threadIdx.x;
        for (int b = t; b < nb; b += 256) cur[b] = bstart[b] + cnt[(size_t)b * nch + c];
        __syncthreads();
        for (int i = beg + t; i < end; i += 256) {
            int d = dst[i];
            int pos = atomicAdd(&cur[d >> BSHIFT], 1);
            unsigned rec = ((unsigned)(d & (BUCKET - 1)) << 17) | (unsigned)src[i];
            tmp[pos] = rec;
        }
        return;
    }
    proj_body<float>(smem, blk - 2 * nch, x, W, as_, v2d, hs, ssrc, sdst_out, n);
}

// standalone proj reading fp16 input
__global__ void proj_half_kernel(const __half* __restrict__ x, const float* __restrict__ W,
                                 const float* __restrict__ as_,
                                 __half* __restrict__ hs, float* __restrict__ ssrc, int n) {
    __shared__ float smem[H * H];
    proj_body<__half>(smem, blockIdx.x, x, W, as_, nullptr, hs, ssrc, nullptr, n);
}

__global__ void bucket_finalize(const unsigned* __restrict__ tmpA, const int* __restrict__ bstartA,
                                int* __restrict__ rowptrA, int* __restrict__ srcsA,
                                int ndstA, int nbA,
                                const unsigned* __restrict__ tmpB, const int* __restrict__ bstartB,
                                int* __restrict__ rowptrB, int* __restrict__ srcsB,
                                int ndstB) {
    __shared__ int cnt[BUCKET];
    __shared__ int sm[BUCKET];
    __shared__ int cur[BUCKET];
    int b = blockIdx.x;
    bool second = b >= nbA;
    const unsigned* tmp = second ? tmpB : tmpA;
    const int* bstart = second ? bstartB : bstartA;
    int* rowptr = second ? rowptrB : rowptrA;
    int* srcs   = second ? srcsB : srcsA;
    int ndst    = second ? ndstB : ndstA;
    if (second) b -= nbA;

    int t = threadIdx.x;
    int base = bstart[b], endi = bstart[b + 1];
    cnt[t] = 0;
    __syncthreads();
    for (int i = base + t; i < endi; i += 512)
        atomicAdd(&cnt[tmp[i] >> 17], 1);
    __syncthreads();
    int c0 = cnt[t];
    sm[t] = c0;
    __syncthreads();
    for (int off = 1; off < 512; off <<= 1) {
        int u = t >= off ? sm[t - off] : 0;
        __syncthreads();
        sm[t] += u;
        __syncthreads();
    }
    int d0 = b << BSHIFT;
    int e = base + sm[t] - c0;
    cur[t] = e;
    if (d0 + t < ndst) rowptr[d0 + t] = e;
    if (t == 0) {
        int hi = d0 + BUCKET;
        if (hi > ndst) hi = ndst;
        rowptr[hi] = endi;
    }
    __syncthreads();
    for (int i = base + t; i < endi; i += 512) {
        unsigned rec = tmp[i];
        int pos = atomicAdd(&cur[rec >> 17], 1);
        srcs[pos] = (int)(rec & 0x1FFFFu);
    }
}

// ---- 1-node-per-wave tiered path ----
template <int P>
__device__ __forceinline__ float gat_fast(const int* __restrict__ srcs, int beg, int cnt,
                                          const float* __restrict__ ssrc, float sdst,
                                          const __half* __restrict__ hs,
                                          const float* __restrict__ bias, int lane) {
    bool valid = lane < cnt;
    int s_l = valid ? srcs[beg + lane] : 0;
    float ss = valid ? ssrc[s_l] : 0.f;

    const __half* hsl = hs + lane;
    __half hv[P];
#pragma unroll
    for (int k = 0; k < P; ++k) {
        hv[k] = hsl[(size_t)bcasti(s_l, k) * H];
    }

    float sc = ss + sdst;
    sc = sc > 0.f ? sc : 0.2f * sc;
    float ev_l = valid ? __expf(sc) : 0.f;
    float ll = ev_l;
#pragma unroll
    for (int off = 32; off; off >>= 1) ll += __shfl_xor(ll, off);

    float acc0 = 0.f, acc1 = 0.f, acc2 = 0.f, acc3 = 0.f;
    float acc4 = 0.f, acc5 = 0.f, acc6 = 0.f, acc7 = 0.f;
#pragma unroll
    for (int k = 0; k < P; k += 8) {
        acc0 += bcastf(ev_l, k + 0) * __half2float(hv[k + 0]);
        acc1 += bcastf(ev_l, k + 1) * __half2float(hv[k + 1]);
        acc2 += bcastf(ev_l, k + 2) * __half2float(hv[k + 2]);
        acc3 += bcastf(ev_l, k + 3) * __half2float(hv[k + 3]);
        acc4 += bcastf(ev_l, k + 4) * __half2float(hv[k + 4]);
        acc5 += bcastf(ev_l, k + 5) * __half2float(hv[k + 5]);
        acc6 += bcastf(ev_l, k + 6) * __half2float(hv[k + 6]);
        acc7 += bcastf(ev_l, k + 7) * __half2float(hv[k + 7]);
    }
    if constexpr (P == 32) {
        int j = P;
        for (; j + 3 < cnt; j += 4) {
            acc0 += bcastf(ev_l, j + 0) * __half2float(hsl[(size_t)bcasti(s_l, j + 0) * H]);
            acc1 += bcastf(ev_l, j + 1) * __half2float(hsl[(size_t)bcasti(s_l, j + 1) * H]);
            acc2 += bcastf(ev_l, j + 2) * __half2float(hsl[(size_t)bcasti(s_l, j + 2) * H]);
            acc3 += bcastf(ev_l, j + 3) * __half2float(hsl[(size_t)bcasti(s_l, j + 3) * H]);
        }
        for (; j < cnt; ++j)
            acc0 += bcastf(ev_l, j) * __half2float(hsl[(size_t)bcasti(s_l, j) * H]);
    }
    float v = ((acc0 + acc1) + (acc2 + acc3)) + ((acc4 + acc5) + (acc6 + acc7));
    v = v / (ll + 1e-16f) + bias[lane];
    return v > 0.f ? v : 0.f;
}

__device__ __forceinline__ float gat_general(const int* __restrict__ srcs, int beg, int end,
                                             const float* __restrict__ ssrc, float sdst,
                                             const __half* __restrict__ hs,
                                             const float* __restrict__ bias, int lane) {
    const __half* hsl = hs + lane;
    float acc0 = 0.f, acc1 = 0.f;
    float mm = -3.4e38f;
    for (int base = beg; base < end; base += 64) {
        int idx = base + lane;
        if (idx < end) {
            float sc = ssrc[srcs[idx]] + sdst;
            sc = sc > 0.f ? sc : 0.2f * sc;
            mm = fmaxf(mm, sc);
        }
    }
#pragma unroll
    for (int off = 32; off; off >>= 1) mm = fmaxf(mm, __shfl_xor(mm, off));
    float ll = 0.f;
    for (int base = beg; base < end; base += 64) {
        int idx = base + lane;
        int c2 = end - base; if (c2 > 64) c2 = 64;
        int s_l = idx < end ? srcs[idx] : 0;
        float ev_l = 0.f;
        if (idx < end) {
            float sc = ssrc[s_l] + sdst;
            sc = sc > 0.f ? sc : 0.2f * sc;
            ev_l = __expf(sc - mm);
        }
        ll += ev_l;
        int j = 0;
        for (; j + 1 < c2; j += 2) {
            acc0 += bcastf(ev_l, j) * __half2float(hsl[(size_t)bcasti(s_l, j) * H]);
            acc1 += bcastf(ev_l, j + 1) * __half2float(hsl[(size_t)bcasti(s_l, j + 1) * H]);
        }
        if (j < c2)
            acc0 += bcastf(ev_l, j) * __half2float(hsl[(size_t)bcasti(s_l, j) * H]);
    }
#pragma unroll
    for (int off = 32; off; off >>= 1) ll += __shfl_xor(ll, off);
    float v = (acc0 + acc1) / (ll + 1e-16f) + bias[lane];
    return v > 0.f ? v : 0.f;
}

__device__ __forceinline__ float gat_aggregate(const int* __restrict__ rowptr,
                                               const int* __restrict__ srcs,
                                               const float* __restrict__ ssrc,
                                               float sdst,
                                               const __half* __restrict__ hs,
                                               const float* __restrict__ bias,
                                               int wid, int lane) {
    int beg = rowptr[wid], end = rowptr[wid + 1];
    int cnt = end - beg;
    if (cnt <= 16) return gat_fast<16>(srcs, beg, cnt, ssrc, sdst, hs, bias, lane);
    if (cnt <= 64) return gat_fast<32>(srcs, beg, cnt, ssrc, sdst, hs, bias, lane);
    return gat_general(srcs, beg, end, ssrc, sdst, hs, bias, lane);
}

// ---- 2-nodes-per-wave half2 gather fast path (gat1) ----
template <int P>
__device__ __forceinline__ float2 gat_pair_fast(const int* __restrict__ srcs,
                                                int r0, int r1, int cnt0, int cnt1,
                                                const float* __restrict__ ssrc,
                                                float sdstA, float sdstB,
                                                const __half* __restrict__ hs,
                                                const float* __restrict__ bias,
                                                int lane) {
    int half = lane >> 5, sub = lane & 31;
    int beg = half ? r1 : r0;
    int cnt = half ? cnt1 : cnt0;
    bool valid = sub < cnt;
    int s_l = valid ? srcs[beg + sub] : 0;
    float ss = valid ? ssrc[s_l] : 0.f;
    float sdst = half ? sdstB : sdstA;

    const __half2* hp = (const __half2*)hs;
    __half2 hv[P];
#pragma unroll
    for (int k = 0; k < P; ++k) {
        int sA = bcasti(s_l, k), sB = bcasti(s_l, 32 + k);
        int srow = half ? sB : sA;
        hv[k] = hp[(size_t)srow * 32 + sub];
    }

    float sc = ss + sdst;
    sc = sc > 0.f ? sc : 0.2f * sc;
    float ev_l = valid ? __expf(sc) : 0.f;
    float ll = ev_l;
#pragma unroll
    for (int off = 16; off; off >>= 1) ll += __shfl_xor(ll, off);

    float ax0 = 0.f, ax1 = 0.f, ax2 = 0.f, ax3 = 0.f;
    float ay0 = 0.f, ay1 = 0.f, ay2 = 0.f, ay3 = 0.f;
#pragma unroll
    for (int k = 0; k < P; k += 4) {
#pragma unroll
        for (int u = 0; u < 4; ++u) {
            float eA = bcastf(ev_l, k + u), eB = bcastf(ev_l, 32 + k + u);
            float e = half ? eB : eA;
            float2 f = __half22float2(hv[k + u]);
            if (u == 0) { ax0 += e * f.x; ay0 += e * f.y; }
            if (u == 1) { ax1 += e * f.x; ay1 += e * f.y; }
            if (u == 2) { ax2 += e * f.x; ay2 += e * f.y; }
            if (u == 3) { ax3 += e * f.x; ay3 += e * f.y; }
        }
    }
    float vx = (ax0 + ax1) + (ax2 + ax3);
    float vy = (ay0 + ay1) + (ay2 + ay3);
    float inv = 1.f / (ll + 1e-16f);
    float2 bv = *(const float2*)(bias + 2 * sub);
    vx = vx * inv + bv.x;
    vy = vy * inv + bv.y;
    vx = vx > 0.f ? vx : 0.f;
    vy = vy > 0.f ? vy : 0.f;
    return make_float2(vx, vy);
}

// gat1: rel1 -> fp16 xiA, 2 nodes/wave
__global__ void gat1_kernel(const int* __restrict__ rp, const int* __restrict__ sr,
                            const float* __restrict__ ssrc, const float* __restrict__ sdstArr,
                            const __half* __restrict__ hs, const float* __restrict__ bias,
                            __half* __restrict__ out, int n) {
    int t = (int)(blockIdx.x * blockDim.x + threadIdx.x);
    int pw = t >> 6, lane = t & 63;
    int wid0 = 2 * pw;
    if (wid0 >= n) return;
    bool has1 = wid0 + 1 < n;
    int r0 = rp[wid0], r1 = rp[wid0 + 1];
    int r2 = has1 ? rp[wid0 + 2] : r1;
    int cnt0 = r1 - r0, cnt1 = r2 - r1;
    int mx = cnt0 > cnt1 ? cnt0 : cnt1;
    int half = lane >> 5, sub = lane & 31;

    if (mx <= 32) {
        float sdstA = sdstArr[wid0];
        float sdstB = has1 ? sdstArr[wid0 + 1] : 0.f;
        float2 v;
        if (mx <= 16) v = gat_pair_fast<16>(sr, r0, r1, cnt0, cnt1, ssrc, sdstA, sdstB, hs, bias, lane);
        else          v = gat_pair_fast<32>(sr, r0, r1, cnt0, cnt1, ssrc, sdstA, sdstB, hs, bias, lane);
        int node = half ? wid0 + 1 : wid0;
        if (!half || has1)
            *(__half2*)(out + (size_t)node * H + 2 * sub) = __float22half2_rn(v);
    } else {
        float v0 = gat_aggregate(rp, sr, ssrc, sdstArr[wid0], hs, bias, wid0, lane);
        out[(size_t)wid0 * H + lane] = __float2half_rn(v0);
        if (has1) {
            float v1 = gat_aggregate(rp, sr, ssrc, sdstArr[wid0 + 1], hs, bias, wid0 + 1, lane);
            out[(size_t)(wid0 + 1) * H + lane] = __float2half_rn(v1);
        }
    }
}

// ---- fused gat0+gat2+MLP: one wave per net node, same CSR for both relations ----
// phase1: rel0 aggregate over hs0 -> v0 -> sdstC in-register
// phase2: rel2 aggregate over hs2 (prefetch issued before phase1 consume) -> v2 -> MLP
template <int P>
__device__ __forceinline__ float gat02_fast(const int* __restrict__ srcs, int beg, int cnt,
                                            const float* __restrict__ ssrc0, float sdst0,
                                            const __half* __restrict__ hs0, const float* __restrict__ bias0,
                                            const float* __restrict__ v2next,
                                            const float* __restrict__ ssrc2,
                                            const __half* __restrict__ hs2, const float* __restrict__ bias2,
                                            int lane) {
    bool valid = lane < cnt;
    int s_l = valid ? srcs[beg + lane] : 0;
    float ss0 = valid ? ssrc0[s_l] : 0.f;
    float ss2 = valid ? ssrc2[s_l] : 0.f;

    const __half* h0 = hs0 + lane;
    const __half* h2 = hs2 + lane;
    __half hv0[P], hv2[P];
#pragma unroll
    for (int k = 0; k < P; ++k) hv0[k] = h0[(size_t)bcasti(s_l, k) * H];
#pragma unroll
    for (int k = 0; k < P; ++k) hv2[k] = h2[(size_t)bcasti(s_l, k) * H];

    // phase-1 weights (overlaps both prefetch batches)
    float sc0 = ss0 + sdst0;
    sc0 = sc0 > 0.f ? sc0 : 0.2f * sc0;
    float ev0 = valid ? __expf(sc0) : 0.f;
    float l0 = ev0;
#pragma unroll
    for (int off = 32; off; off >>= 1) l0 += __shfl_xor(l0, off);

    float a0 = 0.f, a1 = 0.f, a2 = 0.f, a3 = 0.f;
#pragma unroll
    for (int k = 0; k < P; k += 4) {
        a0 += bcastf(ev0, k + 0) * __half2float(hv0[k + 0]);
        a1 += bcastf(ev0, k + 1) * __half2float(hv0[k + 1]);
        a2 += bcastf(ev0, k + 2) * __half2float(hv0[k + 2]);
        a3 += bcastf(ev0, k + 3) * __half2float(hv0[k + 3]);
    }
    if constexpr (P == 32) {
        int j = P;
        for (; j < cnt; ++j)
            a0 += bcastf(ev0, j) * __half2float(h0[(size_t)bcasti(s_l, j) * H]);
    }
    float v0 = ((a0 + a1) + (a2 + a3)) / (l0 + 1e-16f) + bias0[lane];
    v0 = v0 > 0.f ? v0 : 0.f;

    // sdstC in-register (all lanes get the sum)
    float q = v0 * v2next[lane];
#pragma unroll
    for (int off = 32; off; off >>= 1) q += __shfl_xor(q, off);

    // phase-2 weights
    float sc2 = ss2 + q;
    sc2 = sc2 > 0.f ? sc2 : 0.2f * sc2;
    float ev2 = valid ? __expf(sc2) : 0.f;
    float l2 = ev2;
#pragma unroll
    for (int off = 32; off; off >>= 1) l2 += __shfl_xor(l2, off);

    float b0 = 0.f, b1 = 0.f, b2_ = 0.f, b3 = 0.f;
#pragma unroll
    for (int k = 0; k < P; k += 4) {
        b0 += bcastf(ev2, k + 0) * __half2float(hv2[k + 0]);
        b1 += bcastf(ev2, k + 1) * __half2float(hv2[k + 1]);
        b2_ += bcastf(ev2, k + 2) * __half2float(hv2[k + 2]);
        b3 += bcastf(ev2, k + 3) * __half2float(hv2[k + 3]);
    }
    if constexpr (P == 32) {
        int j = P;
        for (; j < cnt; ++j)
            b0 += bcastf(ev2, j) * __half2float(h2[(size_t)bcasti(s_l, j) * H]);
    }
    float v2 = ((b0 + b1) + (b2_ + b3)) / (l2 + 1e-16f) + bias2[lane];
    return v2 > 0.f ? v2 : 0.f;
}

__global__ void gat02_mlp_kernel(const int* __restrict__ rowptr, const int* __restrict__ srcs,
                                 const float* __restrict__ ssrc0, const float* __restrict__ sdst0Arr,
                                 const __half* __restrict__ hs0, const float* __restrict__ bias0,
                                 const float* __restrict__ v2next,
                                 const float* __restrict__ ssrc2, const __half* __restrict__ hs2,
                                 const float* __restrict__ bias2,
                                 const float* __restrict__ w1, const float* __restrict__ b1,
                                 const float* __restrict__ w2, const float* __restrict__ b2,
                                 float* __restrict__ out, int ndst) {
    __shared__ float W1[H * 32];
    __shared__ float W2[32];
    __shared__ float B1[32];
    {
        int t = threadIdx.x;
        for (int i = t; i < H * 32; i += 256) W1[i] = w1[i];
        if (t < 32) { W2[t] = w2[t]; B1[t] = b1[t]; }
        __syncthreads();
    }
    int wid = (int)((blockIdx.x * blockDim.x + threadIdx.x) >> 6);
    int lane = threadIdx.x & 63;
    if (wid >= ndst) return;

    int beg = rowptr[wid], end = rowptr[wid + 1];
    int cnt = end - beg;
    float v;
    if (cnt <= 16) {
        v = gat02_fast<16>(srcs, beg, cnt, ssrc0, sdst0Arr[wid], hs0, bias0,
                           v2next, ssrc2, hs2, bias2, lane);
    } else if (cnt <= 64) {
        v = gat02_fast<32>(srcs, beg, cnt, ssrc0, sdst0Arr[wid], hs0, bias0,
                           v2next, ssrc2, hs2, bias2, lane);
    } else {
        float v0 = gat_general(srcs, beg, end, ssrc0, sdst0Arr[wid], hs0, bias0, lane);
        float q = v0 * v2next[lane];
#pragma unroll
        for (int off = 32; off; off >>= 1) q += __shfl_xor(q, off);
        v = gat_general(srcs, beg, end, ssrc2, q, hs2, bias2, lane);
    }

    int c = lane & 31;
    int kbase = (lane >> 5) << 5;
    float s = 0.f;
#pragma unroll
    for (int k = 0; k < 32; ++k) s += __shfl(v, kbase + k) * W1[(kbase + k) * 32 + c];
    s += __shfl_xor(s, 32);
    s += B1[c];
    s = s > 0.f ? s : 0.f;
    float q = s * W2[c];
#pragma unroll
    for (int off = 16; off; off >>= 1) q += __shfl_xor(q, off);
    if (lane == 0) out[wid] = q + b2[0];
}

extern "C" void kernel_launch(void* const* d_in, const int* in_sizes, int n_in,
                              void* d_out, int out_size, void* d_ws, size_t ws_size,
                              hipStream_t stream) {
    const float* x_inst  = (const float*)d_in[0];
    const float* x_net   = (const float*)d_in[1];
    const int*   e_i2n   = (const int*)d_in[2];
    const int*   e_n2i   = (const int*)d_in[3];
    const float* W_src   = (const float*)d_in[4];
    const float* W_dst   = (const float*)d_in[5];
    const float* att_src = (const float*)d_in[6];
    const float* att_dst = (const float*)d_in[7];
    const float* bias_g  = (const float*)d_in[8];
    const float* lin1_w  = (const float*)d_in[9];
    const float* lin1_b  = (const float*)d_in[10];
    const float* lin2_w  = (const float*)d_in[11];
    const float* lin2_b  = (const float*)d_in[12];

    const int n_inst = in_sizes[0] / H;
    const int n_net  = in_sizes[1] / H;
    const int ne     = in_sizes[2] / 2;
    const int nmax   = n_inst > n_net ? n_inst : n_net;

    const int nbA = (n_net + BUCKET - 1) >> BSHIFT;
    const int nbB = (n_inst + BUCKET - 1) >> BSHIFT;
    const int nch = (ne + CHUNK - 1) / CHUNK;   // must be <= 512

    float* ws = (float*)d_ws;
    size_t off = 0;
    auto alloc = [&](size_t nelem) {
        off = (off + 3) & ~(size_t)3;
        float* p = ws + off; off += nelem; return p;
    };
    __half* xiA    = (__half*)alloc((size_t)n_inst * H / 2);
    __half* hs0    = (__half*)alloc((size_t)nmax * H / 2);
    __half* hs1    = (__half*)alloc((size_t)nmax * H / 2);
    __half* hs2    = (__half*)alloc((size_t)nmax * H / 2);
    float* ssrc0   = alloc(nmax);
    float* ssrc1   = alloc(nmax);
    float* ssrc2   = alloc(nmax);
    float* sdstA   = alloc(nmax);
    float* sdstB   = alloc(nmax);
    int*   rp_i2n  = (int*)alloc(nmax + 1);
    int*   sr_i2n  = (int*)alloc(ne);
    int*   rp_n2i  = (int*)alloc(nmax + 1);
    int*   sr_n2i  = (int*)alloc(ne);
    unsigned* tmpA = (unsigned*)alloc(ne);
    unsigned* tmpB = (unsigned*)alloc(ne);
    int*   cntA    = (int*)alloc((size_t)NBMAX * nch);
    int*   cntB    = (int*)alloc((size_t)NBMAX * nch);
    int*   totA    = (int*)alloc(NBMAX);
    int*   totB    = (int*)alloc(NBMAX);
    int*   bstartA = (int*)alloc(NBMAX + 1);
    int*   bstartB = (int*)alloc(NBMAX + 1);
    float* v2all   = alloc(3 * H);
    (void)ws_size;

    const int* dstA = e_i2n + ne;   // dst = net
    const int* dstB = e_n2i + ne;   // dst = inst

    wvec3_kernel<<<3, 64, 0, stream>>>(W_dst, att_dst, v2all);

    // hist (A+B) || proj0
    {
        int grid = 2 * nch + (n_inst + 15) / 16;
        hist_proj_kernel<<<grid, 256, 0, stream>>>(dstA, dstB, cntA, cntB, ne, nch, nbA, nbB,
                                                   x_inst, W_src + 0 * H * H, att_src + 0 * H,
                                                   v2all + 1 * H, hs0, ssrc0, sdstB, n_inst);
    }
    scan_chunks<<<nbA + nbB, 512, 0, stream>>>(cntA, cntB, totA, totB, nch, nbA);
    scan_buckets<<<2, 256, 0, stream>>>(totA, totB, bstartA, bstartB, nbA, nbB, ne);
    // scatter (A+B) || proj1
    {
        int grid = 2 * nch + (n_net + 15) / 16;
        scatter_proj_kernel<<<grid, 256, 0, stream>>>(e_i2n, dstA, cntA, bstartA, tmpA,
                                                      e_n2i, dstB, cntB, bstartB, tmpB,
                                                      ne, nch, nbA, nbB,
                                                      x_net, W_src + 1 * H * H, att_src + 1 * H,
                                                      v2all + 0 * H, hs1, ssrc1, sdstA, n_net);
    }
    bucket_finalize<<<nbA + nbB, 512, 0, stream>>>(tmpA, bstartA, rp_i2n, sr_i2n, n_net, nbA,
                                                   tmpB, bstartB, rp_n2i, sr_n2i, n_inst);

    // gat1 (rel1 -> fp16 xiA, 2 nodes/wave)
    {
        int npair = (n_inst + 1) / 2;
        gat1_kernel<<<(npair + 3) / 4, 256, 0, stream>>>(rp_n2i, sr_n2i, ssrc1, sdstB,
                                                         hs1, bias_g + 1 * H, xiA, n_inst);
    }
    // proj2: fp16 xiA -> hs2/ssrc2
    proj_half_kernel<<<(n_inst + 15) / 16, 256, 0, stream>>>(xiA, W_src + 2 * H * H,
                                                             att_src + 2 * H, hs2, ssrc2, n_inst);
    // fused gat0+gat2+MLP -> d_out (sdstC never touches memory)
    gat02_mlp_kernel<<<(n_net + 3) / 4, 256, 0, stream>>>(rp_i2n, sr_i2n,
                                                          ssrc0, sdstA, hs0, bias_g + 0 * H,
                                                          v2all + 2 * H,
                                                          ssrc2, hs2, bias_g + 2 * H,
                                                          lin1_w, lin1_b, lin2_w, lin2_b,
                                                          (float*)d_out, n_net);
}

// Round 19
// 306.258 us; speedup vs baseline: 1.0783x; 1.0783x over previous
//
#include <hip/hip_runtime.h>
#include <hip/hip_fp16.h>

#define H 64
#define BSHIFT 9
#define BUCKET 512
#define NBMAX 256
#define CHUNK 4096

__device__ __forceinline__ int bcasti(int x, int j) {
    return __builtin_amdgcn_readlane(x, j);
}
__device__ __forceinline__ float bcastf(float x, int j) {
    return __uint_as_float((unsigned)__builtin_amdgcn_readlane((int)__float_as_uint(x), j));
}

__device__ __forceinline__ float ldf(const float* p) { return *p; }
__device__ __forceinline__ float ldf(const __half* p) { return __half2float(*p); }

// v2all[b][k] = sum_j Wd_b[k][j] * ad_b[j]
__global__ void wvec3_kernel(const float* __restrict__ W_dst, const float* __restrict__ att_dst,
                             float* __restrict__ v2all) {
    int b = blockIdx.x;
    int k = threadIdx.x;
    const float* Wd = W_dst + (size_t)b * H * H;
    const float* ad = att_dst + (size_t)b * H;
    float s2 = 0.f;
    for (int j = 0; j < H; ++j) s2 += Wd[k * H + j] * ad[j];
    v2all[b * H + k] = s2;
}

// ---- proj device body: 16 rows/block, 4 rows/wave; generic output strides ----
// hs write: hs[row*rstride + lane*cstride]; ssrc write: ssrc[row*sstride]
template <typename T>
__device__ __forceinline__ void proj_body(float* __restrict__ Wl, int blk,
                                          const T* __restrict__ x, const float* __restrict__ W,
                                          const float* __restrict__ as_, const float* __restrict__ v2d,
                                          __half* __restrict__ hs, int rstride, int cstride,
                                          float* __restrict__ ssrc, int sstride,
                                          float* __restrict__ sdst_out, int n) {
    int t = threadIdx.x;
    for (int i = t; i < H * H; i += 256) Wl[i] = W[i];
    __syncthreads();
    int lane = t & 63;
    int w = t >> 6;
    int row0 = blk * 16 + w * 4;
    if (row0 >= n) return;
    int rem = n - row0;
    float asl = as_[lane];
    const T* xp = x + (size_t)row0 * H + lane;
    float xr0 = ldf(xp);
    float xr1 = rem > 1 ? ldf(xp + H) : 0.f;
    float xr2 = rem > 2 ? ldf(xp + 2 * H) : 0.f;
    float xr3 = rem > 3 ? ldf(xp + 3 * H) : 0.f;
    float a0 = 0.f, a1 = 0.f, a2 = 0.f, a3 = 0.f;
#pragma unroll
    for (int k = 0; k < H; ++k) {
        float wv = Wl[k * H + lane];
        a0 = fmaf(bcastf(xr0, k), wv, a0);
        a1 = fmaf(bcastf(xr1, k), wv, a1);
        a2 = fmaf(bcastf(xr2, k), wv, a2);
        a3 = fmaf(bcastf(xr3, k), wv, a3);
    }
    __half* hp = hs + (size_t)row0 * rstride + lane * cstride;
    hp[0] = __float2half_rn(a0);
    if (rem > 1) hp[rstride] = __float2half_rn(a1);
    if (rem > 2) hp[2 * rstride] = __float2half_rn(a2);
    if (rem > 3) hp[3 * rstride] = __float2half_rn(a3);
    float p0 = a0 * asl, p1 = a1 * asl, p2 = a2 * asl, p3 = a3 * asl;
#pragma unroll
    for (int off = 32; off; off >>= 1) {
        p0 += __shfl_xor(p0, off); p1 += __shfl_xor(p1, off);
        p2 += __shfl_xor(p2, off); p3 += __shfl_xor(p3, off);
    }
    if (lane == 0) {
        ssrc[(size_t)row0 * sstride] = p0;
        if (rem > 1) ssrc[(size_t)(row0 + 1) * sstride] = p1;
        if (rem > 2) ssrc[(size_t)(row0 + 2) * sstride] = p2;
        if (rem > 3) ssrc[(size_t)(row0 + 3) * sstride] = p3;
    }
    if (sdst_out) {
        float vl = v2d[lane];
        float q0 = xr0 * vl, q1 = xr1 * vl, q2 = xr2 * vl, q3 = xr3 * vl;
#pragma unroll
        for (int off = 32; off; off >>= 1) {
            q0 += __shfl_xor(q0, off); q1 += __shfl_xor(q1, off);
            q2 += __shfl_xor(q2, off); q3 += __shfl_xor(q3, off);
        }
        if (lane == 0) {
            sdst_out[row0] = q0;
            if (rem > 1) sdst_out[row0 + 1] = q1;
            if (rem > 2) sdst_out[row0 + 2] = q2;
            if (rem > 3) sdst_out[row0 + 3] = q3;
        }
    }
}

// ---- fused: part_hist || proj0 (writes interleaved hs02 slot 0, ssrc02 slot 0) ----
__global__ void hist_proj_kernel(const int* __restrict__ dstA, const int* __restrict__ dstB,
                                 int* __restrict__ cntA, int* __restrict__ cntB,
                                 int ne, int nch, int nbA, int nbB,
                                 const float* __restrict__ x, const float* __restrict__ W,
                                 const float* __restrict__ as_, const float* __restrict__ v2d,
                                 __half* __restrict__ hs02, float* __restrict__ ssrc02,
                                 float* __restrict__ sdst_out, int n) {
    __shared__ float smem[H * H];
    int blk = blockIdx.x;
    if (blk < 2 * nch) {
        int* h = (int*)smem;
        bool second = blk >= nch;
        const int* dst = second ? dstB : dstA;
        int* cnt = second ? cntB : cntA;
        int nb = second ? nbB : nbA;
        int c = second ? blk - nch : blk;
        int beg = c * CHUNK, end = beg + CHUNK;
        if (end > ne) end = ne;
        int t = threadIdx.x;
        for (int i = t; i < NBMAX; i += 256) h[i] = 0;
        __syncthreads();
        for (int i = beg + t; i < end; i += 256) atomicAdd(&h[dst[i] >> BSHIFT], 1);
        __syncthreads();
        for (int b = t; b < nb; b += 256) cnt[(size_t)b * nch + c] = h[b];
        return;
    }
    proj_body<float>(smem, blk - 2 * nch, x, W, as_, v2d,
                     hs02, 2 * H, 2, ssrc02, 2, sdst_out, n);
}

__global__ void scan_chunks(int* __restrict__ cntA, int* __restrict__ cntB,
                            int* __restrict__ totA, int* __restrict__ totB,
                            int nch, int nbA) {
    __shared__ int sm[512];
    int b = blockIdx.x;
    bool second = b >= nbA;
    int* cnt = second ? cntB : cntA;
    int* tot = second ? totB : totA;
    if (second) b -= nbA;
    int t = threadIdx.x;
    int v = t < nch ? cnt[(size_t)b * nch + t] : 0;
    sm[t] = v;
    __syncthreads();
    for (int off = 1; off < 512; off <<= 1) {
        int u = t >= off ? sm[t - off] : 0;
        __syncthreads();
        sm[t] += u;
        __syncthreads();
    }
    if (t < nch) cnt[(size_t)b * nch + t] = sm[t] - v;
    if (t == 511) tot[b] = sm[511];
}

__global__ void scan_buckets(const int* __restrict__ totA, const int* __restrict__ totB,
                             int* __restrict__ bstartA, int* __restrict__ bstartB,
                             int nbA, int nbB, int ne) {
    __shared__ int sm[256];
    const int* tot = blockIdx.x ? totB : totA;
    int* bstart = blockIdx.x ? bstartB : bstartA;
    int nb = blockIdx.x ? nbB : nbA;
    int t = threadIdx.x;
    int v = t < nb ? tot[t] : 0;
    sm[t] = v;
    __syncthreads();
    for (int off = 1; off < 256; off <<= 1) {
        int u = t >= off ? sm[t - off] : 0;
        __syncthreads();
        sm[t] += u;
        __syncthreads();
    }
    if (t < nb) bstart[t] = sm[t] - v;
    if (t == 0) bstart[nb] = ne;
}

// ---- fused: part_scatter || proj1 (hs1/ssrc1 standard layout) ----
__global__ void scatter_proj_kernel(const int* __restrict__ srcA, const int* __restrict__ dstA,
                                    const int* __restrict__ cntA, const int* __restrict__ bstartA,
                                    unsigned* __restrict__ tmpA,
                                    const int* __restrict__ srcB, const int* __restrict__ dstB,
                                    const int* __restrict__ cntB, const int* __restrict__ bstartB,
                                    unsigned* __restrict__ tmpB,
                                    int ne, int nch, int nbA, int nbB,
                                    const float* __restrict__ x, const float* __restrict__ W,
                                    const float* __restrict__ as_, const float* __restrict__ v2d,
                                    __half* __restrict__ hs, float* __restrict__ ssrc,
                                    float* __restrict__ sdst_out, int n) {
    __shared__ float smem[H * H];
    int blk = blockIdx.x;
    if (blk < 2 * nch) {
        int* cur = (int*)smem;
        bool second = blk >= nch;
        const int* src = second ? srcB : srcA;
        const int* dst = second ? dstB : dstA;
        const int* cnt = second ? cntB : cntA;
        const int* bstart = second ? bstartB : bstartA;
        unsigned* tmp = second ? tmpB : tmpA;
        int nb = second ? nbB : nbA;
        int c = second ? blk - nch : blk;
        int beg = c * CHUNK, end = beg + CHUNK;
        if (end > ne) end = ne;
        int t = threadIdx.x;
        for (int b = t; b < nb; b += 256) cur[b] = bstart[b] + cnt[(size_t)b * nch + c];
        __syncthreads();
        for (int i = beg + t; i < end; i += 256) {
            int d = dst[i];
            int pos = atomicAdd(&cur[d >> BSHIFT], 1);
            unsigned rec = ((unsigned)(d & (BUCKET - 1)) << 17) | (unsigned)src[i];
            tmp[pos] = rec;
        }
        return;
    }
    proj_body<float>(smem, blk - 2 * nch, x, W, as_, v2d,
                     hs, H, 1, ssrc, 1, sdst_out, n);
}

// standalone proj reading fp16 input, writing interleaved slot 1
__global__ void proj_half_kernel(const __half* __restrict__ x, const float* __restrict__ W,
                                 const float* __restrict__ as_,
                                 __half* __restrict__ hs02, float* __restrict__ ssrc02, int n) {
    __shared__ float smem[H * H];
    proj_body<__half>(smem, blockIdx.x, x, W, as_, nullptr,
                      hs02 + 1, 2 * H, 2, ssrc02 + 1, 2, nullptr, n);
}

__global__ void bucket_finalize(const unsigned* __restrict__ tmpA, const int* __restrict__ bstartA,
                                int* __restrict__ rowptrA, int* __restrict__ srcsA,
                                int ndstA, int nbA,
                                const unsigned* __restrict__ tmpB, const int* __restrict__ bstartB,
                                int* __restrict__ rowptrB, int* __restrict__ srcsB,
                                int ndstB) {
    __shared__ int cnt[BUCKET];
    __shared__ int sm[BUCKET];
    __shared__ int cur[BUCKET];
    int b = blockIdx.x;
    bool second = b >= nbA;
    const unsigned* tmp = second ? tmpB : tmpA;
    const int* bstart = second ? bstartB : bstartA;
    int* rowptr = second ? rowptrB : rowptrA;
    int* srcs   = second ? srcsB : srcsA;
    int ndst    = second ? ndstB : ndstA;
    if (second) b -= nbA;

    int t = threadIdx.x;
    int base = bstart[b], endi = bstart[b + 1];
    cnt[t] = 0;
    __syncthreads();
    for (int i = base + t; i < endi; i += 512)
        atomicAdd(&cnt[tmp[i] >> 17], 1);
    __syncthreads();
    int c0 = cnt[t];
    sm[t] = c0;
    __syncthreads();
    for (int off = 1; off < 512; off <<= 1) {
        int u = t >= off ? sm[t - off] : 0;
        __syncthreads();
        sm[t] += u;
        __syncthreads();
    }
    int d0 = b << BSHIFT;
    int e = base + sm[t] - c0;
    cur[t] = e;
    if (d0 + t < ndst) rowptr[d0 + t] = e;
    if (t == 0) {
        int hi = d0 + BUCKET;
        if (hi > ndst) hi = ndst;
        rowptr[hi] = endi;
    }
    __syncthreads();
    for (int i = base + t; i < endi; i += 512) {
        unsigned rec = tmp[i];
        int pos = atomicAdd(&cur[rec >> 17], 1);
        srcs[pos] = (int)(rec & 0x1FFFFu);
    }
}

// ---- 1-node-per-wave tiered path (hs1 layout) ----
template <int P>
__device__ __forceinline__ float gat_fast(const int* __restrict__ srcs, int beg, int cnt,
                                          const float* __restrict__ ssrc, float sdst,
                                          const __half* __restrict__ hs,
                                          const float* __restrict__ bias, int lane) {
    bool valid = lane < cnt;
    int s_l = valid ? srcs[beg + lane] : 0;
    float ss = valid ? ssrc[s_l] : 0.f;

    const __half* hsl = hs + lane;
    __half hv[P];
#pragma unroll
    for (int k = 0; k < P; ++k) {
        hv[k] = hsl[(size_t)bcasti(s_l, k) * H];
    }

    float sc = ss + sdst;
    sc = sc > 0.f ? sc : 0.2f * sc;
    float ev_l = valid ? __expf(sc) : 0.f;
    float ll = ev_l;
#pragma unroll
    for (int off = 32; off; off >>= 1) ll += __shfl_xor(ll, off);

    float acc0 = 0.f, acc1 = 0.f, acc2 = 0.f, acc3 = 0.f;
    float acc4 = 0.f, acc5 = 0.f, acc6 = 0.f, acc7 = 0.f;
#pragma unroll
    for (int k = 0; k < P; k += 8) {
        acc0 += bcastf(ev_l, k + 0) * __half2float(hv[k + 0]);
        acc1 += bcastf(ev_l, k + 1) * __half2float(hv[k + 1]);
        acc2 += bcastf(ev_l, k + 2) * __half2float(hv[k + 2]);
        acc3 += bcastf(ev_l, k + 3) * __half2float(hv[k + 3]);
        acc4 += bcastf(ev_l, k + 4) * __half2float(hv[k + 4]);
        acc5 += bcastf(ev_l, k + 5) * __half2float(hv[k + 5]);
        acc6 += bcastf(ev_l, k + 6) * __half2float(hv[k + 6]);
        acc7 += bcastf(ev_l, k + 7) * __half2float(hv[k + 7]);
    }
    if constexpr (P == 32) {
        int j = P;
        for (; j + 3 < cnt; j += 4) {
            acc0 += bcastf(ev_l, j + 0) * __half2float(hsl[(size_t)bcasti(s_l, j + 0) * H]);
            acc1 += bcastf(ev_l, j + 1) * __half2float(hsl[(size_t)bcasti(s_l, j + 1) * H]);
            acc2 += bcastf(ev_l, j + 2) * __half2float(hsl[(size_t)bcasti(s_l, j + 2) * H]);
            acc3 += bcastf(ev_l, j + 3) * __half2float(hsl[(size_t)bcasti(s_l, j + 3) * H]);
        }
        for (; j < cnt; ++j)
            acc0 += bcastf(ev_l, j) * __half2float(hsl[(size_t)bcasti(s_l, j) * H]);
    }
    float v = ((acc0 + acc1) + (acc2 + acc3)) + ((acc4 + acc5) + (acc6 + acc7));
    v = v / (ll + 1e-16f) + bias[lane];
    return v > 0.f ? v : 0.f;
}

// general path, generic strides: hs value at hs[s*rstride + lane*cstride], score at ssrc[s*sstride]
__device__ __forceinline__ float gat_general(const int* __restrict__ srcs, int beg, int end,
                                             const float* __restrict__ ssrc, int sstride, float sdst,
                                             const __half* __restrict__ hs, int rstride, int cstride,
                                             const float* __restrict__ bias, int lane) {
    const __half* hsl = hs + lane * cstride;
    float acc0 = 0.f, acc1 = 0.f;
    float mm = -3.4e38f;
    for (int base = beg; base < end; base += 64) {
        int idx = base + lane;
        if (idx < end) {
            float sc = ssrc[(size_t)srcs[idx] * sstride] + sdst;
            sc = sc > 0.f ? sc : 0.2f * sc;
            mm = fmaxf(mm, sc);
        }
    }
#pragma unroll
    for (int off = 32; off; off >>= 1) mm = fmaxf(mm, __shfl_xor(mm, off));
    float ll = 0.f;
    for (int base = beg; base < end; base += 64) {
        int idx = base + lane;
        int c2 = end - base; if (c2 > 64) c2 = 64;
        int s_l = idx < end ? srcs[idx] : 0;
        float ev_l = 0.f;
        if (idx < end) {
            float sc = ssrc[(size_t)s_l * sstride] + sdst;
            sc = sc > 0.f ? sc : 0.2f * sc;
            ev_l = __expf(sc - mm);
        }
        ll += ev_l;
        int j = 0;
        for (; j + 1 < c2; j += 2) {
            acc0 += bcastf(ev_l, j) * __half2float(hsl[(size_t)bcasti(s_l, j) * rstride]);
            acc1 += bcastf(ev_l, j + 1) * __half2float(hsl[(size_t)bcasti(s_l, j + 1) * rstride]);
        }
        if (j < c2)
            acc0 += bcastf(ev_l, j) * __half2float(hsl[(size_t)bcasti(s_l, j) * rstride]);
    }
#pragma unroll
    for (int off = 32; off; off >>= 1) ll += __shfl_xor(ll, off);
    float v = (acc0 + acc1) / (ll + 1e-16f) + bias[lane];
    return v > 0.f ? v : 0.f;
}

__device__ __forceinline__ float gat_aggregate(const int* __restrict__ rowptr,
                                               const int* __restrict__ srcs,
                                               const float* __restrict__ ssrc,
                                               float sdst,
                                               const __half* __restrict__ hs,
                                               const float* __restrict__ bias,
                                               int wid, int lane) {
    int beg = rowptr[wid], end = rowptr[wid + 1];
    int cnt = end - beg;
    if (cnt <= 16) return gat_fast<16>(srcs, beg, cnt, ssrc, sdst, hs, bias, lane);
    if (cnt <= 64) return gat_fast<32>(srcs, beg, cnt, ssrc, sdst, hs, bias, lane);
    return gat_general(srcs, beg, end, ssrc, 1, sdst, hs, H, 1, bias, lane);
}

// ---- 2-nodes-per-wave half2 gather fast path (gat1, hs1 layout) ----
template <int P>
__device__ __forceinline__ float2 gat_pair_fast(const int* __restrict__ srcs,
                                                int r0, int r1, int cnt0, int cnt1,
                                                const float* __restrict__ ssrc,
                                                float sdstA, float sdstB,
                                                const __half* __restrict__ hs,
                                                const float* __restrict__ bias,
                                                int lane) {
    int half = lane >> 5, sub = lane & 31;
    int beg = half ? r1 : r0;
    int cnt = half ? cnt1 : cnt0;
    bool valid = sub < cnt;
    int s_l = valid ? srcs[beg + sub] : 0;
    float ss = valid ? ssrc[s_l] : 0.f;
    float sdst = half ? sdstB : sdstA;

    const __half2* hp = (const __half2*)hs;
    __half2 hv[P];
#pragma unroll
    for (int k = 0; k < P; ++k) {
        int sA = bcasti(s_l, k), sB = bcasti(s_l, 32 + k);
        int srow = half ? sB : sA;
        hv[k] = hp[(size_t)srow * 32 + sub];
    }

    float sc = ss + sdst;
    sc = sc > 0.f ? sc : 0.2f * sc;
    float ev_l = valid ? __expf(sc) : 0.f;
    float ll = ev_l;
#pragma unroll
    for (int off = 16; off; off >>= 1) ll += __shfl_xor(ll, off);

    float ax0 = 0.f, ax1 = 0.f, ax2 = 0.f, ax3 = 0.f;
    float ay0 = 0.f, ay1 = 0.f, ay2 = 0.f, ay3 = 0.f;
#pragma unroll
    for (int k = 0; k < P; k += 4) {
#pragma unroll
        for (int u = 0; u < 4; ++u) {
            float eA = bcastf(ev_l, k + u), eB = bcastf(ev_l, 32 + k + u);
            float e = half ? eB : eA;
            float2 f = __half22float2(hv[k + u]);
            if (u == 0) { ax0 += e * f.x; ay0 += e * f.y; }
            if (u == 1) { ax1 += e * f.x; ay1 += e * f.y; }
            if (u == 2) { ax2 += e * f.x; ay2 += e * f.y; }
            if (u == 3) { ax3 += e * f.x; ay3 += e * f.y; }
        }
    }
    float vx = (ax0 + ax1) + (ax2 + ax3);
    float vy = (ay0 + ay1) + (ay2 + ay3);
    float inv = 1.f / (ll + 1e-16f);
    float2 bv = *(const float2*)(bias + 2 * sub);
    vx = vx * inv + bv.x;
    vy = vy * inv + bv.y;
    vx = vx > 0.f ? vx : 0.f;
    vy = vy > 0.f ? vy : 0.f;
    return make_float2(vx, vy);
}

// gat1: rel1 -> fp16 xiA, 2 nodes/wave
__global__ void gat1_kernel(const int* __restrict__ rp, const int* __restrict__ sr,
                            const float* __restrict__ ssrc, const float* __restrict__ sdstArr,
                            const __half* __restrict__ hs, const float* __restrict__ bias,
                            __half* __restrict__ out, int n) {
    int t = (int)(blockIdx.x * blockDim.x + threadIdx.x);
    int pw = t >> 6, lane = t & 63;
    int wid0 = 2 * pw;
    if (wid0 >= n) return;
    bool has1 = wid0 + 1 < n;
    int r0 = rp[wid0], r1 = rp[wid0 + 1];
    int r2 = has1 ? rp[wid0 + 2] : r1;
    int cnt0 = r1 - r0, cnt1 = r2 - r1;
    int mx = cnt0 > cnt1 ? cnt0 : cnt1;
    int half = lane >> 5, sub = lane & 31;

    if (mx <= 32) {
        float sdstA = sdstArr[wid0];
        float sdstB = has1 ? sdstArr[wid0 + 1] : 0.f;
        float2 v;
        if (mx <= 16) v = gat_pair_fast<16>(sr, r0, r1, cnt0, cnt1, ssrc, sdstA, sdstB, hs, bias, lane);
        else          v = gat_pair_fast<32>(sr, r0, r1, cnt0, cnt1, ssrc, sdstA, sdstB, hs, bias, lane);
        int node = half ? wid0 + 1 : wid0;
        if (!half || has1)
            *(__half2*)(out + (size_t)node * H + 2 * sub) = __float22half2_rn(v);
    } else {
        float v0 = gat_aggregate(rp, sr, ssrc, sdstArr[wid0], hs, bias, wid0, lane);
        out[(size_t)wid0 * H + lane] = __float2half_rn(v0);
        if (has1) {
            float v1 = gat_aggregate(rp, sr, ssrc, sdstArr[wid0 + 1], hs, bias, wid0 + 1, lane);
            out[(size_t)(wid0 + 1) * H + lane] = __float2half_rn(v1);
        }
    }
}

// ---- fused gat0+gat2+MLP with INTERLEAVED hs02/ssrc02: one random row per edge ----
template <int P>
__device__ __forceinline__ float gat02_fast(const int* __restrict__ srcs, int beg, int cnt,
                                            const float* __restrict__ ssrc02, float sdst0,
                                            const __half* __restrict__ hs02,
                                            const float* __restrict__ bias0,
                                            const float* __restrict__ v2next,
                                            const float* __restrict__ bias2,
                                            int lane) {
    bool valid = lane < cnt;
    int s_l = valid ? srcs[beg + lane] : 0;
    float2 sspair = make_float2(0.f, 0.f);
    if (valid) sspair = *(const float2*)(ssrc02 + 2 * (size_t)s_l);

    // one interleaved row fetch per edge: __half2 = (hs0[c], hs2[c])
    const __half2* hrow = (const __half2*)hs02 + lane;
    __half2 hv[P];
#pragma unroll
    for (int k = 0; k < P; ++k) hv[k] = hrow[(size_t)bcasti(s_l, k) * H];

    // phase-1 weights (overlaps prefetch)
    float sc0 = sspair.x + sdst0;
    sc0 = sc0 > 0.f ? sc0 : 0.2f * sc0;
    float ev0 = valid ? __expf(sc0) : 0.f;
    float l0 = ev0;
#pragma unroll
    for (int off = 32; off; off >>= 1) l0 += __shfl_xor(l0, off);

    float a0 = 0.f, a1 = 0.f, a2 = 0.f, a3 = 0.f;
#pragma unroll
    for (int k = 0; k < P; k += 4) {
        a0 += bcastf(ev0, k + 0) * __half2float(__low2half(hv[k + 0]));
        a1 += bcastf(ev0, k + 1) * __half2float(__low2half(hv[k + 1]));
        a2 += bcastf(ev0, k + 2) * __half2float(__low2half(hv[k + 2]));
        a3 += bcastf(ev0, k + 3) * __half2float(__low2half(hv[k + 3]));
    }
    if constexpr (P == 32) {
        for (int j = P; j < cnt; ++j)
            a0 += bcastf(ev0, j) * __half2float(__low2half(hrow[(size_t)bcasti(s_l, j) * H]));
    }
    float v0 = ((a0 + a1) + (a2 + a3)) / (l0 + 1e-16f) + bias0[lane];
    v0 = v0 > 0.f ? v0 : 0.f;

    // sdstC in-register
    float q = v0 * v2next[lane];
#pragma unroll
    for (int off = 32; off; off >>= 1) q += __shfl_xor(q, off);

    // phase-2 weights
    float sc2 = sspair.y + q;
    sc2 = sc2 > 0.f ? sc2 : 0.2f * sc2;
    float ev2 = valid ? __expf(sc2) : 0.f;
    float l2 = ev2;
#pragma unroll
    for (int off = 32; off; off >>= 1) l2 += __shfl_xor(l2, off);

    float b0 = 0.f, b1 = 0.f, b2_ = 0.f, b3 = 0.f;
#pragma unroll
    for (int k = 0; k < P; k += 4) {
        b0 += bcastf(ev2, k + 0) * __half2float(__high2half(hv[k + 0]));
        b1 += bcastf(ev2, k + 1) * __half2float(__high2half(hv[k + 1]));
        b2_ += bcastf(ev2, k + 2) * __half2float(__high2half(hv[k + 2]));
        b3 += bcastf(ev2, k + 3) * __half2float(__high2half(hv[k + 3]));
    }
    if constexpr (P == 32) {
        for (int j = P; j < cnt; ++j)
            b0 += bcastf(ev2, j) * __half2float(__high2half(hrow[(size_t)bcasti(s_l, j) * H]));
    }
    float v2 = ((b0 + b1) + (b2_ + b3)) / (l2 + 1e-16f) + bias2[lane];
    return v2 > 0.f ? v2 : 0.f;
}

__global__ void gat02_mlp_kernel(const int* __restrict__ rowptr, const int* __restrict__ srcs,
                                 const float* __restrict__ ssrc02, const float* __restrict__ sdst0Arr,
                                 const __half* __restrict__ hs02, const float* __restrict__ bias0,
                                 const float* __restrict__ v2next, const float* __restrict__ bias2,
                                 const float* __restrict__ w1, const float* __restrict__ b1,
                                 const float* __restrict__ w2, const float* __restrict__ b2,
                                 float* __restrict__ out, int ndst) {
    __shared__ float W1[H * 32];
    __shared__ float W2[32];
    __shared__ float B1[32];
    {
        int t = threadIdx.x;
        for (int i = t; i < H * 32; i += 256) W1[i] = w1[i];
        if (t < 32) { W2[t] = w2[t]; B1[t] = b1[t]; }
        __syncthreads();
    }
    int wid = (int)((blockIdx.x * blockDim.x + threadIdx.x) >> 6);
    int lane = threadIdx.x & 63;
    if (wid >= ndst) return;

    int beg = rowptr[wid], end = rowptr[wid + 1];
    int cnt = end - beg;
    float v;
    if (cnt <= 16) {
        v = gat02_fast<16>(srcs, beg, cnt, ssrc02, sdst0Arr[wid], hs02, bias0, v2next, bias2, lane);
    } else if (cnt <= 64) {
        v = gat02_fast<32>(srcs, beg, cnt, ssrc02, sdst0Arr[wid], hs02, bias0, v2next, bias2, lane);
    } else {
        float v0 = gat_general(srcs, beg, end, ssrc02, 2, sdst0Arr[wid], hs02, 2 * H, 2, bias0, lane);
        float q = v0 * v2next[lane];
#pragma unroll
        for (int off = 32; off; off >>= 1) q += __shfl_xor(q, off);
        v = gat_general(srcs, beg, end, ssrc02 + 1, 2, q, hs02 + 1, 2 * H, 2, bias2, lane);
    }

    int c = lane & 31;
    int kbase = (lane >> 5) << 5;
    float s = 0.f;
#pragma unroll
    for (int k = 0; k < 32; ++k) s += __shfl(v, kbase + k) * W1[(kbase + k) * 32 + c];
    s += __shfl_xor(s, 32);
    s += B1[c];
    s = s > 0.f ? s : 0.f;
    float q = s * W2[c];
#pragma unroll
    for (int off = 16; off; off >>= 1) q += __shfl_xor(q, off);
    if (lane == 0) out[wid] = q + b2[0];
}

extern "C" void kernel_launch(void* const* d_in, const int* in_sizes, int n_in,
                              void* d_out, int out_size, void* d_ws, size_t ws_size,
                              hipStream_t stream) {
    const float* x_inst  = (const float*)d_in[0];
    const float* x_net   = (const float*)d_in[1];
    const int*   e_i2n   = (const int*)d_in[2];
    const int*   e_n2i   = (const int*)d_in[3];
    const float* W_src   = (const float*)d_in[4];
    const float* W_dst   = (const float*)d_in[5];
    const float* att_src = (const float*)d_in[6];
    const float* att_dst = (const float*)d_in[7];
    const float* bias_g  = (const float*)d_in[8];
    const float* lin1_w  = (const float*)d_in[9];
    const float* lin1_b  = (const float*)d_in[10];
    const float* lin2_w  = (const float*)d_in[11];
    const float* lin2_b  = (const float*)d_in[12];

    const int n_inst = in_sizes[0] / H;
    const int n_net  = in_sizes[1] / H;
    const int ne     = in_sizes[2] / 2;
    const int nmax   = n_inst > n_net ? n_inst : n_net;

    const int nbA = (n_net + BUCKET - 1) >> BSHIFT;
    const int nbB = (n_inst + BUCKET - 1) >> BSHIFT;
    const int nch = (ne + CHUNK - 1) / CHUNK;   // must be <= 512

    float* ws = (float*)d_ws;
    size_t off = 0;
    auto alloc = [&](size_t nelem) {
        off = (off + 3) & ~(size_t)3;
        float* p = ws + off; off += nelem; return p;
    };
    __half* xiA    = (__half*)alloc((size_t)n_inst * H / 2);
    __half* hs02   = (__half*)alloc((size_t)nmax * H);       // interleaved [N][64][2] fp16
    __half* hs1    = (__half*)alloc((size_t)nmax * H / 2);
    float* ssrc02  = alloc((size_t)nmax * 2);                // interleaved (ssrc0, ssrc2)
    float* ssrc1   = alloc(nmax);
    float* sdstA   = alloc(nmax);
    float* sdstB   = alloc(nmax);
    int*   rp_i2n  = (int*)alloc(nmax + 1);
    int*   sr_i2n  = (int*)alloc(ne);
    int*   rp_n2i  = (int*)alloc(nmax + 1);
    int*   sr_n2i  = (int*)alloc(ne);
    unsigned* tmpA = (unsigned*)alloc(ne);
    unsigned* tmpB = (unsigned*)alloc(ne);
    int*   cntA    = (int*)alloc((size_t)NBMAX * nch);
    int*   cntB    = (int*)alloc((size_t)NBMAX * nch);
    int*   totA    = (int*)alloc(NBMAX);
    int*   totB    = (int*)alloc(NBMAX);
    int*   bstartA = (int*)alloc(NBMAX + 1);
    int*   bstartB = (int*)alloc(NBMAX + 1);
    float* v2all   = alloc(3 * H);
    (void)ws_size;

    const int* dstA = e_i2n + ne;   // dst = net
    const int* dstB = e_n2i + ne;   // dst = inst

    wvec3_kernel<<<3, 64, 0, stream>>>(W_dst, att_dst, v2all);

    // hist (A+B) || proj0 -> interleaved slot 0
    {
        int grid = 2 * nch + (n_inst + 15) / 16;
        hist_proj_kernel<<<grid, 256, 0, stream>>>(dstA, dstB, cntA, cntB, ne, nch, nbA, nbB,
                                                   x_inst, W_src + 0 * H * H, att_src + 0 * H,
                                                   v2all + 1 * H, hs02, ssrc02, sdstB, n_inst);
    }
    scan_chunks<<<nbA + nbB, 512, 0, stream>>>(cntA, cntB, totA, totB, nch, nbA);
    scan_buckets<<<2, 256, 0, stream>>>(totA, totB, bstartA, bstartB, nbA, nbB, ne);
    // scatter (A+B) || proj1
    {
        int grid = 2 * nch + (n_net + 15) / 16;
        scatter_proj_kernel<<<grid, 256, 0, stream>>>(e_i2n, dstA, cntA, bstartA, tmpA,
                                                      e_n2i, dstB, cntB, bstartB, tmpB,
                                                      ne, nch, nbA, nbB,
                                                      x_net, W_src + 1 * H * H, att_src + 1 * H,
                                                      v2all + 0 * H, hs1, ssrc1, sdstA, n_net);
    }
    bucket_finalize<<<nbA + nbB, 512, 0, stream>>>(tmpA, bstartA, rp_i2n, sr_i2n, n_net, nbA,
                                                   tmpB, bstartB, rp_n2i, sr_n2i, n_inst);

    // gat1 (rel1 -> fp16 xiA, 2 nodes/wave)
    {
        int npair = (n_inst + 1) / 2;
        gat1_kernel<<<(npair + 3) / 4, 256, 0, stream>>>(rp_n2i, sr_n2i, ssrc1, sdstB,
                                                         hs1, bias_g + 1 * H, xiA, n_inst);
    }
    // proj2: fp16 xiA -> interleaved slot 1
    proj_half_kernel<<<(n_inst + 15) / 16, 256, 0, stream>>>(xiA, W_src + 2 * H * H,
                                                             att_src + 2 * H, hs02, ssrc02, n_inst);
    // fused gat0+gat2+MLP -> d_out (one random row fetch per edge)
    gat02_mlp_kernel<<<(n_net + 3) / 4, 256, 0, stream>>>(rp_i2n, sr_i2n,
                                                          ssrc02, sdstA, hs02, bias_g + 0 * H,
                                                          v2all + 2 * H, bias_g + 2 * H,
                                                          lin1_w, lin1_b, lin2_w, lin2_b,
                                                          (float*)d_out, n_net);
}

// Round 20
// 294.744 us; speedup vs baseline: 1.1204x; 1.0391x over previous
//
#include <hip/hip_runtime.h>
#include <hip/hip_fp16.h>

#define H 64
#define BSHIFT 9
#define BUCKET 512
#define NBMAX 256
#define CHUNK 4096

__device__ __forceinline__ int bcasti(int x, int j) {
    return __builtin_amdgcn_readlane(x, j);
}
__device__ __forceinline__ float bcastf(float x, int j) {
    return __uint_as_float((unsigned)__builtin_amdgcn_readlane((int)__float_as_uint(x), j));
}

__device__ __forceinline__ float ldf(const float* p) { return *p; }
__device__ __forceinline__ float ldf(const __half* p) { return __half2float(*p); }

// v2all[b][k] = sum_j Wd_b[k][j] * ad_b[j]
__global__ void wvec3_kernel(const float* __restrict__ W_dst, const float* __restrict__ att_dst,
                             float* __restrict__ v2all) {
    int b = blockIdx.x;
    int k = threadIdx.x;
    const float* Wd = W_dst + (size_t)b * H * H;
    const float* ad = att_dst + (size_t)b * H;
    float s2 = 0.f;
    for (int j = 0; j < H; ++j) s2 += Wd[k * H + j] * ad[j];
    v2all[b * H + k] = s2;
}

// ---- proj device body: 16 rows/block, 4 rows/wave; generic output strides ----
template <typename T>
__device__ __forceinline__ void proj_body(float* __restrict__ Wl, int blk,
                                          const T* __restrict__ x, const float* __restrict__ W,
                                          const float* __restrict__ as_, const float* __restrict__ v2d,
                                          __half* __restrict__ hs, int rstride, int cstride,
                                          float* __restrict__ ssrc, int sstride,
                                          float* __restrict__ sdst_out, int n) {
    int t = threadIdx.x;
    for (int i = t; i < H * H; i += 256) Wl[i] = W[i];
    __syncthreads();
    int lane = t & 63;
    int w = t >> 6;
    int row0 = blk * 16 + w * 4;
    if (row0 >= n) return;
    int rem = n - row0;
    float asl = as_[lane];
    const T* xp = x + (size_t)row0 * H + lane;
    float xr0 = ldf(xp);
    float xr1 = rem > 1 ? ldf(xp + H) : 0.f;
    float xr2 = rem > 2 ? ldf(xp + 2 * H) : 0.f;
    float xr3 = rem > 3 ? ldf(xp + 3 * H) : 0.f;
    float a0 = 0.f, a1 = 0.f, a2 = 0.f, a3 = 0.f;
#pragma unroll
    for (int k = 0; k < H; ++k) {
        float wv = Wl[k * H + lane];
        a0 = fmaf(bcastf(xr0, k), wv, a0);
        a1 = fmaf(bcastf(xr1, k), wv, a1);
        a2 = fmaf(bcastf(xr2, k), wv, a2);
        a3 = fmaf(bcastf(xr3, k), wv, a3);
    }
    __half* hp = hs + (size_t)row0 * rstride + lane * cstride;
    hp[0] = __float2half_rn(a0);
    if (rem > 1) hp[rstride] = __float2half_rn(a1);
    if (rem > 2) hp[2 * rstride] = __float2half_rn(a2);
    if (rem > 3) hp[3 * rstride] = __float2half_rn(a3);
    float p0 = a0 * asl, p1 = a1 * asl, p2 = a2 * asl, p3 = a3 * asl;
#pragma unroll
    for (int off = 32; off; off >>= 1) {
        p0 += __shfl_xor(p0, off); p1 += __shfl_xor(p1, off);
        p2 += __shfl_xor(p2, off); p3 += __shfl_xor(p3, off);
    }
    if (lane == 0) {
        ssrc[(size_t)row0 * sstride] = p0;
        if (rem > 1) ssrc[(size_t)(row0 + 1) * sstride] = p1;
        if (rem > 2) ssrc[(size_t)(row0 + 2) * sstride] = p2;
        if (rem > 3) ssrc[(size_t)(row0 + 3) * sstride] = p3;
    }
    if (sdst_out) {
        float vl = v2d[lane];
        float q0 = xr0 * vl, q1 = xr1 * vl, q2 = xr2 * vl, q3 = xr3 * vl;
#pragma unroll
        for (int off = 32; off; off >>= 1) {
            q0 += __shfl_xor(q0, off); q1 += __shfl_xor(q1, off);
            q2 += __shfl_xor(q2, off); q3 += __shfl_xor(q3, off);
        }
        if (lane == 0) {
            sdst_out[row0] = q0;
            if (rem > 1) sdst_out[row0 + 1] = q1;
            if (rem > 2) sdst_out[row0 + 2] = q2;
            if (rem > 3) sdst_out[row0 + 3] = q3;
        }
    }
}

// ---- fused: part_hist || proj0 (interleaved slot 0) ----
__global__ void hist_proj_kernel(const int* __restrict__ dstA, const int* __restrict__ dstB,
                                 int* __restrict__ cntA, int* __restrict__ cntB,
                                 int ne, int nch, int nbA, int nbB,
                                 const float* __restrict__ x, const float* __restrict__ W,
                                 const float* __restrict__ as_, const float* __restrict__ v2d,
                                 __half* __restrict__ hs02, float* __restrict__ ssrc02,
                                 float* __restrict__ sdst_out, int n) {
    __shared__ float smem[H * H];
    int blk = blockIdx.x;
    if (blk < 2 * nch) {
        int* h = (int*)smem;
        bool second = blk >= nch;
        const int* dst = second ? dstB : dstA;
        int* cnt = second ? cntB : cntA;
        int nb = second ? nbB : nbA;
        int c = second ? blk - nch : blk;
        int beg = c * CHUNK, end = beg + CHUNK;
        if (end > ne) end = ne;
        int t = threadIdx.x;
        for (int i = t; i < NBMAX; i += 256) h[i] = 0;
        __syncthreads();
        for (int i = beg + t; i < end; i += 256) atomicAdd(&h[dst[i] >> BSHIFT], 1);
        __syncthreads();
        for (int b = t; b < nb; b += 256) cnt[(size_t)b * nch + c] = h[b];
        return;
    }
    proj_body<float>(smem, blk - 2 * nch, x, W, as_, v2d,
                     hs02, 2 * H, 2, ssrc02, 2, sdst_out, n);
}

__global__ void scan_chunks(int* __restrict__ cntA, int* __restrict__ cntB,
                            int* __restrict__ totA, int* __restrict__ totB,
                            int nch, int nbA) {
    __shared__ int sm[512];
    int b = blockIdx.x;
    bool second = b >= nbA;
    int* cnt = second ? cntB : cntA;
    int* tot = second ? totB : totA;
    if (second) b -= nbA;
    int t = threadIdx.x;
    int v = t < nch ? cnt[(size_t)b * nch + t] : 0;
    sm[t] = v;
    __syncthreads();
    for (int off = 1; off < 512; off <<= 1) {
        int u = t >= off ? sm[t - off] : 0;
        __syncthreads();
        sm[t] += u;
        __syncthreads();
    }
    if (t < nch) cnt[(size_t)b * nch + t] = sm[t] - v;
    if (t == 511) tot[b] = sm[511];
}

__global__ void scan_buckets(const int* __restrict__ totA, const int* __restrict__ totB,
                             int* __restrict__ bstartA, int* __restrict__ bstartB,
                             int nbA, int nbB, int ne) {
    __shared__ int sm[256];
    const int* tot = blockIdx.x ? totB : totA;
    int* bstart = blockIdx.x ? bstartB : bstartA;
    int nb = blockIdx.x ? nbB : nbA;
    int t = threadIdx.x;
    int v = t < nb ? tot[t] : 0;
    sm[t] = v;
    __syncthreads();
    for (int off = 1; off < 256; off <<= 1) {
        int u = t >= off ? sm[t - off] : 0;
        __syncthreads();
        sm[t] += u;
        __syncthreads();
    }
    if (t < nb) bstart[t] = sm[t] - v;
    if (t == 0) bstart[nb] = ne;
}

// ---- fused: part_scatter || proj1 ----
__global__ void scatter_proj_kernel(const int* __restrict__ srcA, const int* __restrict__ dstA,
                                    const int* __restrict__ cntA, const int* __restrict__ bstartA,
                                    unsigned* __restrict__ tmpA,
                                    const int* __restrict__ srcB, const int* __restrict__ dstB,
                                    const int* __restrict__ cntB, const int* __restrict__ bstartB,
                                    unsigned* __restrict__ tmpB,
                                    int ne, int nch, int nbA, int nbB,
                                    const float* __restrict__ x, const float* __restrict__ W,
                                    const float* __restrict__ as_, const float* __restrict__ v2d,
                                    __half* __restrict__ hs, float* __restrict__ ssrc,
                                    float* __restrict__ sdst_out, int n) {
    __shared__ float smem[H * H];
    int blk = blockIdx.x;
    if (blk < 2 * nch) {
        int* cur = (int*)smem;
        bool second = blk >= nch;
        const int* src = second ? srcB : srcA;
        const int* dst = second ? dstB : dstA;
        const int* cnt = second ? cntB : cntA;
        const int* bstart = second ? bstartB : bstartA;
        unsigned* tmp = second ? tmpB : tmpA;
        int nb = second ? nbB : nbA;
        int c = second ? blk - nch : blk;
        int beg = c * CHUNK, end = beg + CHUNK;
        if (end > ne) end = ne;
        int t = threadIdx.x;
        for (int b = t; b < nb; b += 256) cur[b] = bstart[b] + cnt[(size_t)b * nch + c];
        __syncthreads();
        for (int i = beg + t; i < end; i += 256) {
            int d = dst[i];
            int pos = atomicAdd(&cur[d >> BSHIFT], 1);
            unsigned rec = ((unsigned)(d & (BUCKET - 1)) << 17) | (unsigned)src[i];
            tmp[pos] = rec;
        }
        return;
    }
    proj_body<float>(smem, blk - 2 * nch, x, W, as_, v2d,
                     hs, H, 1, ssrc, 1, sdst_out, n);
}

// standalone proj reading fp16 input, writing interleaved slot 1
__global__ void proj_half_kernel(const __half* __restrict__ x, const float* __restrict__ W,
                                 const float* __restrict__ as_,
                                 __half* __restrict__ hs02, float* __restrict__ ssrc02, int n) {
    __shared__ float smem[H * H];
    proj_body<__half>(smem, blockIdx.x, x, W, as_, nullptr,
                      hs02 + 1, 2 * H, 2, ssrc02 + 1, 2, nullptr, n);
}

__global__ void bucket_finalize(const unsigned* __restrict__ tmpA, const int* __restrict__ bstartA,
                                int* __restrict__ rowptrA, int* __restrict__ srcsA,
                                int ndstA, int nbA,
                                const unsigned* __restrict__ tmpB, const int* __restrict__ bstartB,
                                int* __restrict__ rowptrB, int* __restrict__ srcsB,
                                int ndstB) {
    __shared__ int cnt[BUCKET];
    __shared__ int sm[BUCKET];
    __shared__ int cur[BUCKET];
    int b = blockIdx.x;
    bool second = b >= nbA;
    const unsigned* tmp = second ? tmpB : tmpA;
    const int* bstart = second ? bstartB : bstartA;
    int* rowptr = second ? rowptrB : rowptrA;
    int* srcs   = second ? srcsB : srcsA;
    int ndst    = second ? ndstB : ndstA;
    if (second) b -= nbA;

    int t = threadIdx.x;
    int base = bstart[b], endi = bstart[b + 1];
    cnt[t] = 0;
    __syncthreads();
    for (int i = base + t; i < endi; i += 512)
        atomicAdd(&cnt[tmp[i] >> 17], 1);
    __syncthreads();
    int c0 = cnt[t];
    sm[t] = c0;
    __syncthreads();
    for (int off = 1; off < 512; off <<= 1) {
        int u = t >= off ? sm[t - off] : 0;
        __syncthreads();
        sm[t] += u;
        __syncthreads();
    }
    int d0 = b << BSHIFT;
    int e = base + sm[t] - c0;
    cur[t] = e;
    if (d0 + t < ndst) rowptr[d0 + t] = e;
    if (t == 0) {
        int hi = d0 + BUCKET;
        if (hi > ndst) hi = ndst;
        rowptr[hi] = endi;
    }
    __syncthreads();
    for (int i = base + t; i < endi; i += 512) {
        unsigned rec = tmp[i];
        int pos = atomicAdd(&cur[rec >> 17], 1);
        srcs[pos] = (int)(rec & 0x1FFFFu);
    }
}

// ---- 1-node-per-wave tiered path (hs1 layout) ----
template <int P>
__device__ __forceinline__ float gat_fast(const int* __restrict__ srcs, int beg, int cnt,
                                          const float* __restrict__ ssrc, float sdst,
                                          const __half* __restrict__ hs,
                                          const float* __restrict__ bias, int lane) {
    bool valid = lane < cnt;
    int s_l = valid ? srcs[beg + lane] : 0;
    float ss = valid ? ssrc[s_l] : 0.f;

    const __half* hsl = hs + lane;
    __half hv[P];
#pragma unroll
    for (int k = 0; k < P; ++k) {
        hv[k] = hsl[(size_t)bcasti(s_l, k) * H];
    }

    float sc = ss + sdst;
    sc = sc > 0.f ? sc : 0.2f * sc;
    float ev_l = valid ? __expf(sc) : 0.f;
    float ll = ev_l;
#pragma unroll
    for (int off = 32; off; off >>= 1) ll += __shfl_xor(ll, off);

    float acc0 = 0.f, acc1 = 0.f, acc2 = 0.f, acc3 = 0.f;
    float acc4 = 0.f, acc5 = 0.f, acc6 = 0.f, acc7 = 0.f;
#pragma unroll
    for (int k = 0; k < P; k += 8) {
        acc0 += bcastf(ev_l, k + 0) * __half2float(hv[k + 0]);
        acc1 += bcastf(ev_l, k + 1) * __half2float(hv[k + 1]);
        acc2 += bcastf(ev_l, k + 2) * __half2float(hv[k + 2]);
        acc3 += bcastf(ev_l, k + 3) * __half2float(hv[k + 3]);
        acc4 += bcastf(ev_l, k + 4) * __half2float(hv[k + 4]);
        acc5 += bcastf(ev_l, k + 5) * __half2float(hv[k + 5]);
        acc6 += bcastf(ev_l, k + 6) * __half2float(hv[k + 6]);
        acc7 += bcastf(ev_l, k + 7) * __half2float(hv[k + 7]);
    }
    if constexpr (P == 32) {
        int j = P;
        for (; j + 3 < cnt; j += 4) {
            acc0 += bcastf(ev_l, j + 0) * __half2float(hsl[(size_t)bcasti(s_l, j + 0) * H]);
            acc1 += bcastf(ev_l, j + 1) * __half2float(hsl[(size_t)bcasti(s_l, j + 1) * H]);
            acc2 += bcastf(ev_l, j + 2) * __half2float(hsl[(size_t)bcasti(s_l, j + 2) * H]);
            acc3 += bcastf(ev_l, j + 3) * __half2float(hsl[(size_t)bcasti(s_l, j + 3) * H]);
        }
        for (; j < cnt; ++j)
            acc0 += bcastf(ev_l, j) * __half2float(hsl[(size_t)bcasti(s_l, j) * H]);
    }
    float v = ((acc0 + acc1) + (acc2 + acc3)) + ((acc4 + acc5) + (acc6 + acc7));
    v = v / (ll + 1e-16f) + bias[lane];
    return v > 0.f ? v : 0.f;
}

// general path, generic strides
__device__ __forceinline__ float gat_general(const int* __restrict__ srcs, int beg, int end,
                                             const float* __restrict__ ssrc, int sstride, float sdst,
                                             const __half* __restrict__ hs, int rstride, int cstride,
                                             const float* __restrict__ bias, int lane) {
    const __half* hsl = hs + lane * cstride;
    float acc0 = 0.f, acc1 = 0.f;
    float mm = -3.4e38f;
    for (int base = beg; base < end; base += 64) {
        int idx = base + lane;
        if (idx < end) {
            float sc = ssrc[(size_t)srcs[idx] * sstride] + sdst;
            sc = sc > 0.f ? sc : 0.2f * sc;
            mm = fmaxf(mm, sc);
        }
    }
#pragma unroll
    for (int off = 32; off; off >>= 1) mm = fmaxf(mm, __shfl_xor(mm, off));
    float ll = 0.f;
    for (int base = beg; base < end; base += 64) {
        int idx = base + lane;
        int c2 = end - base; if (c2 > 64) c2 = 64;
        int s_l = idx < end ? srcs[idx] : 0;
        float ev_l = 0.f;
        if (idx < end) {
            float sc = ssrc[(size_t)s_l * sstride] + sdst;
            sc = sc > 0.f ? sc : 0.2f * sc;
            ev_l = __expf(sc - mm);
        }
        ll += ev_l;
        int j = 0;
        for (; j + 1 < c2; j += 2) {
            acc0 += bcastf(ev_l, j) * __half2float(hsl[(size_t)bcasti(s_l, j) * rstride]);
            acc1 += bcastf(ev_l, j + 1) * __half2float(hsl[(size_t)bcasti(s_l, j + 1) * rstride]);
        }
        if (j < c2)
            acc0 += bcastf(ev_l, j) * __half2float(hsl[(size_t)bcasti(s_l, j) * rstride]);
    }
#pragma unroll
    for (int off = 32; off; off >>= 1) ll += __shfl_xor(ll, off);
    float v = (acc0 + acc1) / (ll + 1e-16f) + bias[lane];
    return v > 0.f ? v : 0.f;
}

__device__ __forceinline__ float gat_aggregate(const int* __restrict__ rowptr,
                                               const int* __restrict__ srcs,
                                               const float* __restrict__ ssrc,
                                               float sdst,
                                               const __half* __restrict__ hs,
                                               const float* __restrict__ bias,
                                               int wid, int lane) {
    int beg = rowptr[wid], end = rowptr[wid + 1];
    int cnt = end - beg;
    if (cnt <= 16) return gat_fast<16>(srcs, beg, cnt, ssrc, sdst, hs, bias, lane);
    if (cnt <= 64) return gat_fast<32>(srcs, beg, cnt, ssrc, sdst, hs, bias, lane);
    return gat_general(srcs, beg, end, ssrc, 1, sdst, hs, H, 1, bias, lane);
}

// ---- 2-nodes-per-wave half2 gather fast path (gat1): shfl (ds_bpermute) broadcast ----
template <int P>
__device__ __forceinline__ float2 gat_pair_fast(const int* __restrict__ srcs,
                                                int r0, int r1, int cnt0, int cnt1,
                                                const float* __restrict__ ssrc,
                                                float sdstA, float sdstB,
                                                const __half* __restrict__ hs,
                                                const float* __restrict__ bias,
                                                int lane) {
    int half = lane >> 5, sub = lane & 31;
    int hbase = half << 5;      // 0 for node A lanes, 32 for node B lanes
    int beg = half ? r1 : r0;
    int cnt = half ? cnt1 : cnt0;
    bool valid = sub < cnt;
    int s_l = valid ? srcs[beg + sub] : 0;
    float ss = valid ? ssrc[s_l] : 0.f;
    float sdst = half ? sdstB : sdstA;

    const __half2* hp = (const __half2*)hs;
    __half2 hv[P];
#pragma unroll
    for (int k = 0; k < P; ++k) {
        int srow = __shfl(s_l, hbase + k);   // ds_bpermute: per-half broadcast, no select
        hv[k] = hp[(size_t)srow * 32 + sub];
    }

    float sc = ss + sdst;
    sc = sc > 0.f ? sc : 0.2f * sc;
    float ev_l = valid ? __expf(sc) : 0.f;
    float ll = ev_l;
#pragma unroll
    for (int off = 16; off; off >>= 1) ll += __shfl_xor(ll, off);

    float ax0 = 0.f, ax1 = 0.f, ax2 = 0.f, ax3 = 0.f;
    float ay0 = 0.f, ay1 = 0.f, ay2 = 0.f, ay3 = 0.f;
#pragma unroll
    for (int k = 0; k < P; k += 4) {
#pragma unroll
        for (int u = 0; u < 4; ++u) {
            float e = __shfl(ev_l, hbase + k + u);   // ds_bpermute, no cndmask
            float2 f = __half22float2(hv[k + u]);
            if (u == 0) { ax0 += e * f.x; ay0 += e * f.y; }
            if (u == 1) { ax1 += e * f.x; ay1 += e * f.y; }
            if (u == 2) { ax2 += e * f.x; ay2 += e * f.y; }
            if (u == 3) { ax3 += e * f.x; ay3 += e * f.y; }
        }
    }
    float vx = (ax0 + ax1) + (ax2 + ax3);
    float vy = (ay0 + ay1) + (ay2 + ay3);
    float inv = 1.f / (ll + 1e-16f);
    float2 bv = *(const float2*)(bias + 2 * sub);
    vx = vx * inv + bv.x;
    vy = vy * inv + bv.y;
    vx = vx > 0.f ? vx : 0.f;
    vy = vy > 0.f ? vy : 0.f;
    return make_float2(vx, vy);
}

// gat1: rel1 -> fp16 xiA, 2 nodes/wave
__global__ void gat1_kernel(const int* __restrict__ rp, const int* __restrict__ sr,
                            const float* __restrict__ ssrc, const float* __restrict__ sdstArr,
                            const __half* __restrict__ hs, const float* __restrict__ bias,
                            __half* __restrict__ out, int n) {
    int t = (int)(blockIdx.x * blockDim.x + threadIdx.x);
    int pw = t >> 6, lane = t & 63;
    int wid0 = 2 * pw;
    if (wid0 >= n) return;
    bool has1 = wid0 + 1 < n;
    int r0 = rp[wid0], r1 = rp[wid0 + 1];
    int r2 = has1 ? rp[wid0 + 2] : r1;
    int cnt0 = r1 - r0, cnt1 = r2 - r1;
    int mx = cnt0 > cnt1 ? cnt0 : cnt1;
    int half = lane >> 5, sub = lane & 31;

    if (mx <= 32) {
        float sdstA = sdstArr[wid0];
        float sdstB = has1 ? sdstArr[wid0 + 1] : 0.f;
        float2 v;
        if (mx <= 16) v = gat_pair_fast<16>(sr, r0, r1, cnt0, cnt1, ssrc, sdstA, sdstB, hs, bias, lane);
        else          v = gat_pair_fast<32>(sr, r0, r1, cnt0, cnt1, ssrc, sdstA, sdstB, hs, bias, lane);
        int node = half ? wid0 + 1 : wid0;
        if (!half || has1)
            *(__half2*)(out + (size_t)node * H + 2 * sub) = __float22half2_rn(v);
    } else {
        float v0 = gat_aggregate(rp, sr, ssrc, sdstArr[wid0], hs, bias, wid0, lane);
        out[(size_t)wid0 * H + lane] = __float2half_rn(v0);
        if (has1) {
            float v1 = gat_aggregate(rp, sr, ssrc, sdstArr[wid0 + 1], hs, bias, wid0 + 1, lane);
            out[(size_t)(wid0 + 1) * H + lane] = __float2half_rn(v1);
        }
    }
}

// ---- fused gat0+gat2+MLP with interleaved hs02/ssrc02 ----
template <int P>
__device__ __forceinline__ float gat02_fast(const int* __restrict__ srcs, int beg, int cnt,
                                            const float* __restrict__ ssrc02, float sdst0,
                                            const __half* __restrict__ hs02,
                                            const float* __restrict__ bias0,
                                            const float* __restrict__ v2next,
                                            const float* __restrict__ bias2,
                                            int lane) {
    bool valid = lane < cnt;
    int s_l = valid ? srcs[beg + lane] : 0;
    float2 sspair = make_float2(0.f, 0.f);
    if (valid) sspair = *(const float2*)(ssrc02 + 2 * (size_t)s_l);

    const __half2* hrow = (const __half2*)hs02 + lane;
    __half2 hv[P];
#pragma unroll
    for (int k = 0; k < P; ++k) hv[k] = hrow[(size_t)bcasti(s_l, k) * H];

    float sc0 = sspair.x + sdst0;
    sc0 = sc0 > 0.f ? sc0 : 0.2f * sc0;
    float ev0 = valid ? __expf(sc0) : 0.f;
    float l0 = ev0;
#pragma unroll
    for (int off = 32; off; off >>= 1) l0 += __shfl_xor(l0, off);

    float a0 = 0.f, a1 = 0.f, a2 = 0.f, a3 = 0.f;
#pragma unroll
    for (int k = 0; k < P; k += 4) {
        a0 += bcastf(ev0, k + 0) * __half2float(__low2half(hv[k + 0]));
        a1 += bcastf(ev0, k + 1) * __half2float(__low2half(hv[k + 1]));
        a2 += bcastf(ev0, k + 2) * __half2float(__low2half(hv[k + 2]));
        a3 += bcastf(ev0, k + 3) * __half2float(__low2half(hv[k + 3]));
    }
    if constexpr (P == 32) {
        for (int j = P; j < cnt; ++j)
            a0 += bcastf(ev0, j) * __half2float(__low2half(hrow[(size_t)bcasti(s_l, j) * H]));
    }
    float v0 = ((a0 + a1) + (a2 + a3)) / (l0 + 1e-16f) + bias0[lane];
    v0 = v0 > 0.f ? v0 : 0.f;

    float q = v0 * v2next[lane];
#pragma unroll
    for (int off = 32; off; off >>= 1) q += __shfl_xor(q, off);

    float sc2 = sspair.y + q;
    sc2 = sc2 > 0.f ? sc2 : 0.2f * sc2;
    float ev2 = valid ? __expf(sc2) : 0.f;
    float l2 = ev2;
#pragma unroll
    for (int off = 32; off; off >>= 1) l2 += __shfl_xor(l2, off);

    float b0 = 0.f, b1 = 0.f, b2_ = 0.f, b3 = 0.f;
#pragma unroll
    for (int k = 0; k < P; k += 4) {
        b0 += bcastf(ev2, k + 0) * __half2float(__high2half(hv[k + 0]));
        b1 += bcastf(ev2, k + 1) * __half2float(__high2half(hv[k + 1]));
        b2_ += bcastf(ev2, k + 2) * __half2float(__high2half(hv[k + 2]));
        b3 += bcastf(ev2, k + 3) * __half2float(__high2half(hv[k + 3]));
    }
    if constexpr (P == 32) {
        for (int j = P; j < cnt; ++j)
            b0 += bcastf(ev2, j) * __half2float(__high2half(hrow[(size_t)bcasti(s_l, j) * H]));
    }
    float v2 = ((b0 + b1) + (b2_ + b3)) / (l2 + 1e-16f) + bias2[lane];
    return v2 > 0.f ? v2 : 0.f;
}

__global__ void gat02_mlp_kernel(const int* __restrict__ rowptr, const int* __restrict__ srcs,
                                 const float* __restrict__ ssrc02, const float* __restrict__ sdst0Arr,
                                 const __half* __restrict__ hs02, const float* __restrict__ bias0,
                                 const float* __restrict__ v2next, const float* __restrict__ bias2,
                                 const float* __restrict__ w1, const float* __restrict__ b1,
                                 const float* __restrict__ w2, const float* __restrict__ b2,
                                 float* __restrict__ out, int ndst) {
    __shared__ float W1[H * 32];
    __shared__ float W2[32];
    __shared__ float B1[32];
    {
        int t = threadIdx.x;
        for (int i = t; i < H * 32; i += 256) W1[i] = w1[i];
        if (t < 32) { W2[t] = w2[t]; B1[t] = b1[t]; }
        __syncthreads();
    }
    int wid = (int)((blockIdx.x * blockDim.x + threadIdx.x) >> 6);
    int lane = threadIdx.x & 63;
    if (wid >= ndst) return;

    int beg = rowptr[wid], end = rowptr[wid + 1];
    int cnt = end - beg;
    float v;
    if (cnt <= 16) {
        v = gat02_fast<16>(srcs, beg, cnt, ssrc02, sdst0Arr[wid], hs02, bias0, v2next, bias2, lane);
    } else if (cnt <= 64) {
        v = gat02_fast<32>(srcs, beg, cnt, ssrc02, sdst0Arr[wid], hs02, bias0, v2next, bias2, lane);
    } else {
        float v0 = gat_general(srcs, beg, end, ssrc02, 2, sdst0Arr[wid], hs02, 2 * H, 2, bias0, lane);
        float q = v0 * v2next[lane];
#pragma unroll
        for (int off = 32; off; off >>= 1) q += __shfl_xor(q, off);
        v = gat_general(srcs, beg, end, ssrc02 + 1, 2, q, hs02 + 1, 2 * H, 2, bias2, lane);
    }

    int c = lane & 31;
    int kbase = (lane >> 5) << 5;
    float s = 0.f;
#pragma unroll
    for (int k = 0; k < 32; ++k) s += __shfl(v, kbase + k) * W1[(kbase + k) * 32 + c];
    s += __shfl_xor(s, 32);
    s += B1[c];
    s = s > 0.f ? s : 0.f;
    float q = s * W2[c];
#pragma unroll
    for (int off = 16; off; off >>= 1) q += __shfl_xor(q, off);
    if (lane == 0) out[wid] = q + b2[0];
}

extern "C" void kernel_launch(void* const* d_in, const int* in_sizes, int n_in,
                              void* d_out, int out_size, void* d_ws, size_t ws_size,
                              hipStream_t stream) {
    const float* x_inst  = (const float*)d_in[0];
    const float* x_net   = (const float*)d_in[1];
    const int*   e_i2n   = (const int*)d_in[2];
    const int*   e_n2i   = (const int*)d_in[3];
    const float* W_src   = (const float*)d_in[4];
    const float* W_dst   = (const float*)d_in[5];
    const float* att_src = (const float*)d_in[6];
    const float* att_dst = (const float*)d_in[7];
    const float* bias_g  = (const float*)d_in[8];
    const float* lin1_w  = (const float*)d_in[9];
    const float* lin1_b  = (const float*)d_in[10];
    const float* lin2_w  = (const float*)d_in[11];
    const float* lin2_b  = (const float*)d_in[12];

    const int n_inst = in_sizes[0] / H;
    const int n_net  = in_sizes[1] / H;
    const int ne     = in_sizes[2] / 2;
    const int nmax   = n_inst > n_net ? n_inst : n_net;

    const int nbA = (n_net + BUCKET - 1) >> BSHIFT;
    const int nbB = (n_inst + BUCKET - 1) >> BSHIFT;
    const int nch = (ne + CHUNK - 1) / CHUNK;   // must be <= 512

    float* ws = (float*)d_ws;
    size_t off = 0;
    auto alloc = [&](size_t nelem) {
        off = (off + 3) & ~(size_t)3;
        float* p = ws + off; off += nelem; return p;
    };
    __half* xiA    = (__half*)alloc((size_t)n_inst * H / 2);
    __half* hs02   = (__half*)alloc((size_t)nmax * H);       // interleaved [N][64][2] fp16
    __half* hs1    = (__half*)alloc((size_t)nmax * H / 2);
    float* ssrc02  = alloc((size_t)nmax * 2);
    float* ssrc1   = alloc(nmax);
    float* sdstA   = alloc(nmax);
    float* sdstB   = alloc(nmax);
    int*   rp_i2n  = (int*)alloc(nmax + 1);
    int*   sr_i2n  = (int*)alloc(ne);
    int*   rp_n2i  = (int*)alloc(nmax + 1);
    int*   sr_n2i  = (int*)alloc(ne);
    unsigned* tmpA = (unsigned*)alloc(ne);
    unsigned* tmpB = (unsigned*)alloc(ne);
    int*   cntA    = (int*)alloc((size_t)NBMAX * nch);
    int*   cntB    = (int*)alloc((size_t)NBMAX * nch);
    int*   totA    = (int*)alloc(NBMAX);
    int*   totB    = (int*)alloc(NBMAX);
    int*   bstartA = (int*)alloc(NBMAX + 1);
    int*   bstartB = (int*)alloc(NBMAX + 1);
    float* v2all   = alloc(3 * H);
    (void)ws_size;

    const int* dstA = e_i2n + ne;   // dst = net
    const int* dstB = e_n2i + ne;   // dst = inst

    wvec3_kernel<<<3, 64, 0, stream>>>(W_dst, att_dst, v2all);

    // hist (A+B) || proj0 -> interleaved slot 0
    {
        int grid = 2 * nch + (n_inst + 15) / 16;
        hist_proj_kernel<<<grid, 256, 0, stream>>>(dstA, dstB, cntA, cntB, ne, nch, nbA, nbB,
                                                   x_inst, W_src + 0 * H * H, att_src + 0 * H,
                                                   v2all + 1 * H, hs02, ssrc02, sdstB, n_inst);
    }
    scan_chunks<<<nbA + nbB, 512, 0, stream>>>(cntA, cntB, totA, totB, nch, nbA);
    scan_buckets<<<2, 256, 0, stream>>>(totA, totB, bstartA, bstartB, nbA, nbB, ne);
    // scatter (A+B) || proj1
    {
        int grid = 2 * nch + (n_net + 15) / 16;
        scatter_proj_kernel<<<grid, 256, 0, stream>>>(e_i2n, dstA, cntA, bstartA, tmpA,
                                                      e_n2i, dstB, cntB, bstartB, tmpB,
                                                      ne, nch, nbA, nbB,
                                                      x_net, W_src + 1 * H * H, att_src + 1 * H,
                                                      v2all + 0 * H, hs1, ssrc1, sdstA, n_net);
    }
    bucket_finalize<<<nbA + nbB, 512, 0, stream>>>(tmpA, bstartA, rp_i2n, sr_i2n, n_net, nbA,
                                                   tmpB, bstartB, rp_n2i, sr_n2i, n_inst);

    // gat1 (rel1 -> fp16 xiA, 2 nodes/wave, bpermute broadcast)
    {
        int npair = (n_inst + 1) / 2;
        gat1_kernel<<<(npair + 3) / 4, 256, 0, stream>>>(rp_n2i, sr_n2i, ssrc1, sdstB,
                                                         hs1, bias_g + 1 * H, xiA, n_inst);
    }
    // proj2: fp16 xiA -> interleaved slot 1
    proj_half_kernel<<<(n_inst + 15) / 16, 256, 0, stream>>>(xiA, W_src + 2 * H * H,
                                                             att_src + 2 * H, hs02, ssrc02, n_inst);
    // fused gat0+gat2+MLP -> d_out
    gat02_mlp_kernel<<<(n_net + 3) / 4, 256, 0, stream>>>(rp_i2n, sr_i2n,
                                                          ssrc02, sdstA, hs02, bias_g + 0 * H,
                                                          v2all + 2 * H, bias_g + 2 * H,
                                                          lin1_w, lin1_b, lin2_w, lin2_b,
                                                          (float*)d_out, n_net);
}

// Round 21
// 294.411 us; speedup vs baseline: 1.1217x; 1.0011x over previous
//
#include <hip/hip_runtime.h>
#include <hip/hip_fp16.h>

#define H 64
#define BSHIFT 9
#define BUCKET 512
#define NBMAX 256
#define CHUNK 4096

__device__ __forceinline__ int bcasti(int x, int j) {
    return __builtin_amdgcn_readlane(x, j);
}
__device__ __forceinline__ float bcastf(float x, int j) {
    return __uint_as_float((unsigned)__builtin_amdgcn_readlane((int)__float_as_uint(x), j));
}

__device__ __forceinline__ float ldf(const float* p) { return *p; }
__device__ __forceinline__ float ldf(const __half* p) { return __half2float(*p); }

// packed-half2 dot-accumulate: acc += hv.lo*w.lo + hv.hi*w.hi
__device__ __forceinline__ float dot2acc(unsigned hv, unsigned w, float acc) {
#if __has_builtin(__builtin_amdgcn_fdot2)
    typedef _Float16 h2_t __attribute__((ext_vector_type(2)));
    return __builtin_amdgcn_fdot2(__builtin_bit_cast(h2_t, hv),
                                  __builtin_bit_cast(h2_t, w), acc, false);
#else
    __half2 h = __builtin_bit_cast(__half2, hv);
    __half2 x = __builtin_bit_cast(__half2, w);
    float2 hf = __half22float2(h), xf = __half22float2(x);
    return acc + hf.x * xf.x + hf.y * xf.y;
#endif
}

// v2all[b][k] = sum_j Wd_b[k][j] * ad_b[j]
__global__ void wvec3_kernel(const float* __restrict__ W_dst, const float* __restrict__ att_dst,
                             float* __restrict__ v2all) {
    int b = blockIdx.x;
    int k = threadIdx.x;
    const float* Wd = W_dst + (size_t)b * H * H;
    const float* ad = att_dst + (size_t)b * H;
    float s2 = 0.f;
    for (int j = 0; j < H; ++j) s2 += Wd[k * H + j] * ad[j];
    v2all[b * H + k] = s2;
}

// ---- proj device body: 16 rows/block, 4 rows/wave; generic output strides ----
template <typename T>
__device__ __forceinline__ void proj_body(float* __restrict__ Wl, int blk,
                                          const T* __restrict__ x, const float* __restrict__ W,
                                          const float* __restrict__ as_, const float* __restrict__ v2d,
                                          __half* __restrict__ hs, int rstride, int cstride,
                                          float* __restrict__ ssrc, int sstride,
                                          float* __restrict__ sdst_out, int n) {
    int t = threadIdx.x;
    for (int i = t; i < H * H; i += 256) Wl[i] = W[i];
    __syncthreads();
    int lane = t & 63;
    int w = t >> 6;
    int row0 = blk * 16 + w * 4;
    if (row0 >= n) return;
    int rem = n - row0;
    float asl = as_[lane];
    const T* xp = x + (size_t)row0 * H + lane;
    float xr0 = ldf(xp);
    float xr1 = rem > 1 ? ldf(xp + H) : 0.f;
    float xr2 = rem > 2 ? ldf(xp + 2 * H) : 0.f;
    float xr3 = rem > 3 ? ldf(xp + 3 * H) : 0.f;
    float a0 = 0.f, a1 = 0.f, a2 = 0.f, a3 = 0.f;
#pragma unroll
    for (int k = 0; k < H; ++k) {
        float wv = Wl[k * H + lane];
        a0 = fmaf(bcastf(xr0, k), wv, a0);
        a1 = fmaf(bcastf(xr1, k), wv, a1);
        a2 = fmaf(bcastf(xr2, k), wv, a2);
        a3 = fmaf(bcastf(xr3, k), wv, a3);
    }
    __half* hp = hs + (size_t)row0 * rstride + lane * cstride;
    hp[0] = __float2half_rn(a0);
    if (rem > 1) hp[rstride] = __float2half_rn(a1);
    if (rem > 2) hp[2 * rstride] = __float2half_rn(a2);
    if (rem > 3) hp[3 * rstride] = __float2half_rn(a3);
    float p0 = a0 * asl, p1 = a1 * asl, p2 = a2 * asl, p3 = a3 * asl;
#pragma unroll
    for (int off = 32; off; off >>= 1) {
        p0 += __shfl_xor(p0, off); p1 += __shfl_xor(p1, off);
        p2 += __shfl_xor(p2, off); p3 += __shfl_xor(p3, off);
    }
    if (lane == 0) {
        ssrc[(size_t)row0 * sstride] = p0;
        if (rem > 1) ssrc[(size_t)(row0 + 1) * sstride] = p1;
        if (rem > 2) ssrc[(size_t)(row0 + 2) * sstride] = p2;
        if (rem > 3) ssrc[(size_t)(row0 + 3) * sstride] = p3;
    }
    if (sdst_out) {
        float vl = v2d[lane];
        float q0 = xr0 * vl, q1 = xr1 * vl, q2 = xr2 * vl, q3 = xr3 * vl;
#pragma unroll
        for (int off = 32; off; off >>= 1) {
            q0 += __shfl_xor(q0, off); q1 += __shfl_xor(q1, off);
            q2 += __shfl_xor(q2, off); q3 += __shfl_xor(q3, off);
        }
        if (lane == 0) {
            sdst_out[row0] = q0;
            if (rem > 1) sdst_out[row0 + 1] = q1;
            if (rem > 2) sdst_out[row0 + 2] = q2;
            if (rem > 3) sdst_out[row0 + 3] = q3;
        }
    }
}

// ---- fused: part_hist || proj0 (interleaved slot 0) ----
__global__ void hist_proj_kernel(const int* __restrict__ dstA, const int* __restrict__ dstB,
                                 int* __restrict__ cntA, int* __restrict__ cntB,
                                 int ne, int nch, int nbA, int nbB,
                                 const float* __restrict__ x, const float* __restrict__ W,
                                 const float* __restrict__ as_, const float* __restrict__ v2d,
                                 __half* __restrict__ hs02, float* __restrict__ ssrc02,
                                 float* __restrict__ sdst_out, int n) {
    __shared__ float smem[H * H];
    int blk = blockIdx.x;
    if (blk < 2 * nch) {
        int* h = (int*)smem;
        bool second = blk >= nch;
        const int* dst = second ? dstB : dstA;
        int* cnt = second ? cntB : cntA;
        int nb = second ? nbB : nbA;
        int c = second ? blk - nch : blk;
        int beg = c * CHUNK, end = beg + CHUNK;
        if (end > ne) end = ne;
        int t = threadIdx.x;
        for (int i = t; i < NBMAX; i += 256) h[i] = 0;
        __syncthreads();
        for (int i = beg + t; i < end; i += 256) atomicAdd(&h[dst[i] >> BSHIFT], 1);
        __syncthreads();
        for (int b = t; b < nb; b += 256) cnt[(size_t)b * nch + c] = h[b];
        return;
    }
    proj_body<float>(smem, blk - 2 * nch, x, W, as_, v2d,
                     hs02, 2 * H, 2, ssrc02, 2, sdst_out, n);
}

__global__ void scan_chunks(int* __restrict__ cntA, int* __restrict__ cntB,
                            int* __restrict__ totA, int* __restrict__ totB,
                            int nch, int nbA) {
    __shared__ int sm[512];
    int b = blockIdx.x;
    bool second = b >= nbA;
    int* cnt = second ? cntB : cntA;
    int* tot = second ? totB : totA;
    if (second) b -= nbA;
    int t = threadIdx.x;
    int v = t < nch ? cnt[(size_t)b * nch + t] : 0;
    sm[t] = v;
    __syncthreads();
    for (int off = 1; off < 512; off <<= 1) {
        int u = t >= off ? sm[t - off] : 0;
        __syncthreads();
        sm[t] += u;
        __syncthreads();
    }
    if (t < nch) cnt[(size_t)b * nch + t] = sm[t] - v;
    if (t == 511) tot[b] = sm[511];
}

__global__ void scan_buckets(const int* __restrict__ totA, const int* __restrict__ totB,
                             int* __restrict__ bstartA, int* __restrict__ bstartB,
                             int nbA, int nbB, int ne) {
    __shared__ int sm[256];
    const int* tot = blockIdx.x ? totB : totA;
    int* bstart = blockIdx.x ? bstartB : bstartA;
    int nb = blockIdx.x ? nbB : nbA;
    int t = threadIdx.x;
    int v = t < nb ? tot[t] : 0;
    sm[t] = v;
    __syncthreads();
    for (int off = 1; off < 256; off <<= 1) {
        int u = t >= off ? sm[t - off] : 0;
        __syncthreads();
        sm[t] += u;
        __syncthreads();
    }
    if (t < nb) bstart[t] = sm[t] - v;
    if (t == 0) bstart[nb] = ne;
}

// ---- fused: part_scatter || proj1 ----
__global__ void scatter_proj_kernel(const int* __restrict__ srcA, const int* __restrict__ dstA,
                                    const int* __restrict__ cntA, const int* __restrict__ bstartA,
                                    unsigned* __restrict__ tmpA,
                                    const int* __restrict__ srcB, const int* __restrict__ dstB,
                                    const int* __restrict__ cntB, const int* __restrict__ bstartB,
                                    unsigned* __restrict__ tmpB,
                                    int ne, int nch, int nbA, int nbB,
                                    const float* __restrict__ x, const float* __restrict__ W,
                                    const float* __restrict__ as_, const float* __restrict__ v2d,
                                    __half* __restrict__ hs, float* __restrict__ ssrc,
                                    float* __restrict__ sdst_out, int n) {
    __shared__ float smem[H * H];
    int blk = blockIdx.x;
    if (blk < 2 * nch) {
        int* cur = (int*)smem;
        bool second = blk >= nch;
        const int* src = second ? srcB : srcA;
        const int* dst = second ? dstB : dstA;
        const int* cnt = second ? cntB : cntA;
        const int* bstart = second ? bstartB : bstartA;
        unsigned* tmp = second ? tmpB : tmpA;
        int nb = second ? nbB : nbA;
        int c = second ? blk - nch : blk;
        int beg = c * CHUNK, end = beg + CHUNK;
        if (end > ne) end = ne;
        int t = threadIdx.x;
        for (int b = t; b < nb; b += 256) cur[b] = bstart[b] + cnt[(size_t)b * nch + c];
        __syncthreads();
        for (int i = beg + t; i < end; i += 256) {
            int d = dst[i];
            int pos = atomicAdd(&cur[d >> BSHIFT], 1);
            unsigned rec = ((unsigned)(d & (BUCKET - 1)) << 17) | (unsigned)src[i];
            tmp[pos] = rec;
        }
        return;
    }
    proj_body<float>(smem, blk - 2 * nch, x, W, as_, v2d,
                     hs, H, 1, ssrc, 1, sdst_out, n);
}

// standalone proj reading fp16 input, writing interleaved slot 1
__global__ void proj_half_kernel(const __half* __restrict__ x, const float* __restrict__ W,
                                 const float* __restrict__ as_,
                                 __half* __restrict__ hs02, float* __restrict__ ssrc02, int n) {
    __shared__ float smem[H * H];
    proj_body<__half>(smem, blockIdx.x, x, W, as_, nullptr,
                      hs02 + 1, 2 * H, 2, ssrc02 + 1, 2, nullptr, n);
}

__global__ void bucket_finalize(const unsigned* __restrict__ tmpA, const int* __restrict__ bstartA,
                                int* __restrict__ rowptrA, int* __restrict__ srcsA,
                                int ndstA, int nbA,
                                const unsigned* __restrict__ tmpB, const int* __restrict__ bstartB,
                                int* __restrict__ rowptrB, int* __restrict__ srcsB,
                                int ndstB) {
    __shared__ int cnt[BUCKET];
    __shared__ int sm[BUCKET];
    __shared__ int cur[BUCKET];
    int b = blockIdx.x;
    bool second = b >= nbA;
    const unsigned* tmp = second ? tmpB : tmpA;
    const int* bstart = second ? bstartB : bstartA;
    int* rowptr = second ? rowptrB : rowptrA;
    int* srcs   = second ? srcsB : srcsA;
    int ndst    = second ? ndstB : ndstA;
    if (second) b -= nbA;

    int t = threadIdx.x;
    int base = bstart[b], endi = bstart[b + 1];
    cnt[t] = 0;
    __syncthreads();
    for (int i = base + t; i < endi; i += 512)
        atomicAdd(&cnt[tmp[i] >> 17], 1);
    __syncthreads();
    int c0 = cnt[t];
    sm[t] = c0;
    __syncthreads();
    for (int off = 1; off < 512; off <<= 1) {
        int u = t >= off ? sm[t - off] : 0;
        __syncthreads();
        sm[t] += u;
        __syncthreads();
    }
    int d0 = b << BSHIFT;
    int e = base + sm[t] - c0;
    cur[t] = e;
    if (d0 + t < ndst) rowptr[d0 + t] = e;
    if (t == 0) {
        int hi = d0 + BUCKET;
        if (hi > ndst) hi = ndst;
        rowptr[hi] = endi;
    }
    __syncthreads();
    for (int i = base + t; i < endi; i += 512) {
        unsigned rec = tmp[i];
        int pos = atomicAdd(&cur[rec >> 17], 1);
        srcs[pos] = (int)(rec & 0x1FFFFu);
    }
}

// ---- 1-node-per-wave tiered path (hs1 layout) ----
template <int P>
__device__ __forceinline__ float gat_fast(const int* __restrict__ srcs, int beg, int cnt,
                                          const float* __restrict__ ssrc, float sdst,
                                          const __half* __restrict__ hs,
                                          const float* __restrict__ bias, int lane) {
    bool valid = lane < cnt;
    int s_l = valid ? srcs[beg + lane] : 0;
    float ss = valid ? ssrc[s_l] : 0.f;

    const __half* hsl = hs + lane;
    __half hv[P];
#pragma unroll
    for (int k = 0; k < P; ++k) {
        hv[k] = hsl[(size_t)bcasti(s_l, k) * H];
    }

    float sc = ss + sdst;
    sc = sc > 0.f ? sc : 0.2f * sc;
    float ev_l = valid ? __expf(sc) : 0.f;
    float ll = ev_l;
#pragma unroll
    for (int off = 32; off; off >>= 1) ll += __shfl_xor(ll, off);

    float acc0 = 0.f, acc1 = 0.f, acc2 = 0.f, acc3 = 0.f;
    float acc4 = 0.f, acc5 = 0.f, acc6 = 0.f, acc7 = 0.f;
#pragma unroll
    for (int k = 0; k < P; k += 8) {
        acc0 += bcastf(ev_l, k + 0) * __half2float(hv[k + 0]);
        acc1 += bcastf(ev_l, k + 1) * __half2float(hv[k + 1]);
        acc2 += bcastf(ev_l, k + 2) * __half2float(hv[k + 2]);
        acc3 += bcastf(ev_l, k + 3) * __half2float(hv[k + 3]);
        acc4 += bcastf(ev_l, k + 4) * __half2float(hv[k + 4]);
        acc5 += bcastf(ev_l, k + 5) * __half2float(hv[k + 5]);
        acc6 += bcastf(ev_l, k + 6) * __half2float(hv[k + 6]);
        acc7 += bcastf(ev_l, k + 7) * __half2float(hv[k + 7]);
    }
    if constexpr (P == 32) {
        int j = P;
        for (; j + 3 < cnt; j += 4) {
            acc0 += bcastf(ev_l, j + 0) * __half2float(hsl[(size_t)bcasti(s_l, j + 0) * H]);
            acc1 += bcastf(ev_l, j + 1) * __half2float(hsl[(size_t)bcasti(s_l, j + 1) * H]);
            acc2 += bcastf(ev_l, j + 2) * __half2float(hsl[(size_t)bcasti(s_l, j + 2) * H]);
            acc3 += bcastf(ev_l, j + 3) * __half2float(hsl[(size_t)bcasti(s_l, j + 3) * H]);
        }
        for (; j < cnt; ++j)
            acc0 += bcastf(ev_l, j) * __half2float(hsl[(size_t)bcasti(s_l, j) * H]);
    }
    float v = ((acc0 + acc1) + (acc2 + acc3)) + ((acc4 + acc5) + (acc6 + acc7));
    v = v / (ll + 1e-16f) + bias[lane];
    return v > 0.f ? v : 0.f;
}

// general path, generic strides
__device__ __forceinline__ float gat_general(const int* __restrict__ srcs, int beg, int end,
                                             const float* __restrict__ ssrc, int sstride, float sdst,
                                             const __half* __restrict__ hs, int rstride, int cstride,
                                             const float* __restrict__ bias, int lane) {
    const __half* hsl = hs + lane * cstride;
    float acc0 = 0.f, acc1 = 0.f;
    float mm = -3.4e38f;
    for (int base = beg; base < end; base += 64) {
        int idx = base + lane;
        if (idx < end) {
            float sc = ssrc[(size_t)srcs[idx] * sstride] + sdst;
            sc = sc > 0.f ? sc : 0.2f * sc;
            mm = fmaxf(mm, sc);
        }
    }
#pragma unroll
    for (int off = 32; off; off >>= 1) mm = fmaxf(mm, __shfl_xor(mm, off));
    float ll = 0.f;
    for (int base = beg; base < end; base += 64) {
        int idx = base + lane;
        int c2 = end - base; if (c2 > 64) c2 = 64;
        int s_l = idx < end ? srcs[idx] : 0;
        float ev_l = 0.f;
        if (idx < end) {
            float sc = ssrc[(size_t)s_l * sstride] + sdst;
            sc = sc > 0.f ? sc : 0.2f * sc;
            ev_l = __expf(sc - mm);
        }
        ll += ev_l;
        int j = 0;
        for (; j + 1 < c2; j += 2) {
            acc0 += bcastf(ev_l, j) * __half2float(hsl[(size_t)bcasti(s_l, j) * rstride]);
            acc1 += bcastf(ev_l, j + 1) * __half2float(hsl[(size_t)bcasti(s_l, j + 1) * rstride]);
        }
        if (j < c2)
            acc0 += bcastf(ev_l, j) * __half2float(hsl[(size_t)bcasti(s_l, j) * rstride]);
    }
#pragma unroll
    for (int off = 32; off; off >>= 1) ll += __shfl_xor(ll, off);
    float v = (acc0 + acc1) / (ll + 1e-16f) + bias[lane];
    return v > 0.f ? v : 0.f;
}

__device__ __forceinline__ float gat_aggregate(const int* __restrict__ rowptr,
                                               const int* __restrict__ srcs,
                                               const float* __restrict__ ssrc,
                                               float sdst,
                                               const __half* __restrict__ hs,
                                               const float* __restrict__ bias,
                                               int wid, int lane) {
    int beg = rowptr[wid], end = rowptr[wid + 1];
    int cnt = end - beg;
    if (cnt <= 16) return gat_fast<16>(srcs, beg, cnt, ssrc, sdst, hs, bias, lane);
    if (cnt <= 64) return gat_fast<32>(srcs, beg, cnt, ssrc, sdst, hs, bias, lane);
    return gat_general(srcs, beg, end, ssrc, 1, sdst, hs, H, 1, bias, lane);
}

// ---- 2-nodes-per-wave half2 gather fast path (gat1): shfl (ds_bpermute) broadcast ----
template <int P>
__device__ __forceinline__ float2 gat_pair_fast(const int* __restrict__ srcs,
                                                int r0, int r1, int cnt0, int cnt1,
                                                const float* __restrict__ ssrc,
                                                float sdstA, float sdstB,
                                                const __half* __restrict__ hs,
                                                const float* __restrict__ bias,
                                                int lane) {
    int half = lane >> 5, sub = lane & 31;
    int hbase = half << 5;
    int beg = half ? r1 : r0;
    int cnt = half ? cnt1 : cnt0;
    bool valid = sub < cnt;
    int s_l = valid ? srcs[beg + sub] : 0;
    float ss = valid ? ssrc[s_l] : 0.f;
    float sdst = half ? sdstB : sdstA;

    const __half2* hp = (const __half2*)hs;
    __half2 hv[P];
#pragma unroll
    for (int k = 0; k < P; ++k) {
        int srow = __shfl(s_l, hbase + k);
        hv[k] = hp[(size_t)srow * 32 + sub];
    }

    float sc = ss + sdst;
    sc = sc > 0.f ? sc : 0.2f * sc;
    float ev_l = valid ? __expf(sc) : 0.f;
    float ll = ev_l;
#pragma unroll
    for (int off = 16; off; off >>= 1) ll += __shfl_xor(ll, off);

    float ax0 = 0.f, ax1 = 0.f, ax2 = 0.f, ax3 = 0.f;
    float ay0 = 0.f, ay1 = 0.f, ay2 = 0.f, ay3 = 0.f;
#pragma unroll
    for (int k = 0; k < P; k += 4) {
#pragma unroll
        for (int u = 0; u < 4; ++u) {
            float e = __shfl(ev_l, hbase + k + u);
            float2 f = __half22float2(hv[k + u]);
            if (u == 0) { ax0 += e * f.x; ay0 += e * f.y; }
            if (u == 1) { ax1 += e * f.x; ay1 += e * f.y; }
            if (u == 2) { ax2 += e * f.x; ay2 += e * f.y; }
            if (u == 3) { ax3 += e * f.x; ay3 += e * f.y; }
        }
    }
    float vx = (ax0 + ax1) + (ax2 + ax3);
    float vy = (ay0 + ay1) + (ay2 + ay3);
    float inv = 1.f / (ll + 1e-16f);
    float2 bv = *(const float2*)(bias + 2 * sub);
    vx = vx * inv + bv.x;
    vy = vy * inv + bv.y;
    vx = vx > 0.f ? vx : 0.f;
    vy = vy > 0.f ? vy : 0.f;
    return make_float2(vx, vy);
}

// gat1: rel1 -> fp16 xiA, 2 nodes/wave
__global__ void gat1_kernel(const int* __restrict__ rp, const int* __restrict__ sr,
                            const float* __restrict__ ssrc, const float* __restrict__ sdstArr,
                            const __half* __restrict__ hs, const float* __restrict__ bias,
                            __half* __restrict__ out, int n) {
    int t = (int)(blockIdx.x * blockDim.x + threadIdx.x);
    int pw = t >> 6, lane = t & 63;
    int wid0 = 2 * pw;
    if (wid0 >= n) return;
    bool has1 = wid0 + 1 < n;
    int r0 = rp[wid0], r1 = rp[wid0 + 1];
    int r2 = has1 ? rp[wid0 + 2] : r1;
    int cnt0 = r1 - r0, cnt1 = r2 - r1;
    int mx = cnt0 > cnt1 ? cnt0 : cnt1;
    int half = lane >> 5, sub = lane & 31;

    if (mx <= 32) {
        float sdstA = sdstArr[wid0];
        float sdstB = has1 ? sdstArr[wid0 + 1] : 0.f;
        float2 v;
        if (mx <= 16) v = gat_pair_fast<16>(sr, r0, r1, cnt0, cnt1, ssrc, sdstA, sdstB, hs, bias, lane);
        else          v = gat_pair_fast<32>(sr, r0, r1, cnt0, cnt1, ssrc, sdstA, sdstB, hs, bias, lane);
        int node = half ? wid0 + 1 : wid0;
        if (!half || has1)
            *(__half2*)(out + (size_t)node * H + 2 * sub) = __float22half2_rn(v);
    } else {
        float v0 = gat_aggregate(rp, sr, ssrc, sdstArr[wid0], hs, bias, wid0, lane);
        out[(size_t)wid0 * H + lane] = __float2half_rn(v0);
        if (has1) {
            float v1 = gat_aggregate(rp, sr, ssrc, sdstArr[wid0 + 1], hs, bias, wid0 + 1, lane);
            out[(size_t)(wid0 + 1) * H + lane] = __float2half_rn(v1);
        }
    }
}

// ---- fused gat0+gat2+MLP with interleaved hs02/ssrc02, v_dot2 consume ----
template <int P>
__device__ __forceinline__ float gat02_fast(const int* __restrict__ srcs, int beg, int cnt,
                                            const float* __restrict__ ssrc02, float sdst0,
                                            const __half* __restrict__ hs02,
                                            const float* __restrict__ bias0,
                                            const float* __restrict__ v2next,
                                            const float* __restrict__ bias2,
                                            int lane) {
    bool valid = lane < cnt;
    int s_l = valid ? srcs[beg + lane] : 0;
    float2 sspair = make_float2(0.f, 0.f);
    if (valid) sspair = *(const float2*)(ssrc02 + 2 * (size_t)s_l);

    // one interleaved row fetch per edge: uint = (hs0[c], hs2[c]) packed halves
    const unsigned* hrow = (const unsigned*)hs02 + lane;
    unsigned hv[P];
#pragma unroll
    for (int k = 0; k < P; ++k) hv[k] = hrow[(size_t)bcasti(s_l, k) * H];

    // phase-1 weights (overlaps prefetch); pack ev0 into low half of a uint
    float sc0 = sspair.x + sdst0;
    sc0 = sc0 > 0.f ? sc0 : 0.2f * sc0;
    float ev0 = valid ? __expf(sc0) : 0.f;
    float l0 = ev0;
#pragma unroll
    for (int off = 32; off; off >>= 1) l0 += __shfl_xor(l0, off);
    unsigned pw0 = (unsigned)__half_as_ushort(__float2half_rn(ev0));   // (ev0, 0)

    float a0 = 0.f, a1 = 0.f, a2 = 0.f, a3 = 0.f;
#pragma unroll
    for (int k = 0; k < P; k += 4) {
        a0 = dot2acc(hv[k + 0], (unsigned)bcasti((int)pw0, k + 0), a0);
        a1 = dot2acc(hv[k + 1], (unsigned)bcasti((int)pw0, k + 1), a1);
        a2 = dot2acc(hv[k + 2], (unsigned)bcasti((int)pw0, k + 2), a2);
        a3 = dot2acc(hv[k + 3], (unsigned)bcasti((int)pw0, k + 3), a3);
    }
    if constexpr (P == 32) {
        for (int j = P; j < cnt; ++j)
            a0 = dot2acc(hrow[(size_t)bcasti(s_l, j) * H], (unsigned)bcasti((int)pw0, j), a0);
    }
    float v0 = ((a0 + a1) + (a2 + a3)) / (l0 + 1e-16f) + bias0[lane];
    v0 = v0 > 0.f ? v0 : 0.f;

    // sdstC in-register
    float q = v0 * v2next[lane];
#pragma unroll
    for (int off = 32; off; off >>= 1) q += __shfl_xor(q, off);

    // phase-2 weights; pack ev2 into HIGH half
    float sc2 = sspair.y + q;
    sc2 = sc2 > 0.f ? sc2 : 0.2f * sc2;
    float ev2 = valid ? __expf(sc2) : 0.f;
    float l2 = ev2;
#pragma unroll
    for (int off = 32; off; off >>= 1) l2 += __shfl_xor(l2, off);
    unsigned pw2 = ((unsigned)__half_as_ushort(__float2half_rn(ev2))) << 16;   // (0, ev2)

    float b0 = 0.f, b1 = 0.f, b2_ = 0.f, b3 = 0.f;
#pragma unroll
    for (int k = 0; k < P; k += 4) {
        b0 = dot2acc(hv[k + 0], (unsigned)bcasti((int)pw2, k + 0), b0);
        b1 = dot2acc(hv[k + 1], (unsigned)bcasti((int)pw2, k + 1), b1);
        b2_ = dot2acc(hv[k + 2], (unsigned)bcasti((int)pw2, k + 2), b2_);
        b3 = dot2acc(hv[k + 3], (unsigned)bcasti((int)pw2, k + 3), b3);
    }
    if constexpr (P == 32) {
        for (int j = P; j < cnt; ++j)
            b0 = dot2acc(hrow[(size_t)bcasti(s_l, j) * H], (unsigned)bcasti((int)pw2, j), b0);
    }
    float v2 = ((b0 + b1) + (b2_ + b3)) / (l2 + 1e-16f) + bias2[lane];
    return v2 > 0.f ? v2 : 0.f;
}

__global__ void gat02_mlp_kernel(const int* __restrict__ rowptr, const int* __restrict__ srcs,
                                 const float* __restrict__ ssrc02, const float* __restrict__ sdst0Arr,
                                 const __half* __restrict__ hs02, const float* __restrict__ bias0,
                                 const float* __restrict__ v2next, const float* __restrict__ bias2,
                                 const float* __restrict__ w1, const float* __restrict__ b1,
                                 const float* __restrict__ w2, const float* __restrict__ b2,
                                 float* __restrict__ out, int ndst) {
    __shared__ float W1[H * 32];
    __shared__ float W2[32];
    __shared__ float B1[32];
    {
        int t = threadIdx.x;
        for (int i = t; i < H * 32; i += 256) W1[i] = w1[i];
        if (t < 32) { W2[t] = w2[t]; B1[t] = b1[t]; }
        __syncthreads();
    }
    int wid = (int)((blockIdx.x * blockDim.x + threadIdx.x) >> 6);
    int lane = threadIdx.x & 63;
    if (wid >= ndst) return;

    int beg = rowptr[wid], end = rowptr[wid + 1];
    int cnt = end - beg;
    float v;
    if (cnt <= 16) {
        v = gat02_fast<16>(srcs, beg, cnt, ssrc02, sdst0Arr[wid], hs02, bias0, v2next, bias2, lane);
    } else if (cnt <= 64) {
        v = gat02_fast<32>(srcs, beg, cnt, ssrc02, sdst0Arr[wid], hs02, bias0, v2next, bias2, lane);
    } else {
        float v0 = gat_general(srcs, beg, end, ssrc02, 2, sdst0Arr[wid], hs02, 2 * H, 2, bias0, lane);
        float q = v0 * v2next[lane];
#pragma unroll
        for (int off = 32; off; off >>= 1) q += __shfl_xor(q, off);
        v = gat_general(srcs, beg, end, ssrc02 + 1, 2, q, hs02 + 1, 2 * H, 2, bias2, lane);
    }

    int c = lane & 31;
    int kbase = (lane >> 5) << 5;
    float s = 0.f;
#pragma unroll
    for (int k = 0; k < 32; ++k) s += __shfl(v, kbase + k) * W1[(kbase + k) * 32 + c];
    s += __shfl_xor(s, 32);
    s += B1[c];
    s = s > 0.f ? s : 0.f;
    float q = s * W2[c];
#pragma unroll
    for (int off = 16; off; off >>= 1) q += __shfl_xor(q, off);
    if (lane == 0) out[wid] = q + b2[0];
}

extern "C" void kernel_launch(void* const* d_in, const int* in_sizes, int n_in,
                              void* d_out, int out_size, void* d_ws, size_t ws_size,
                              hipStream_t stream) {
    const float* x_inst  = (const float*)d_in[0];
    const float* x_net   = (const float*)d_in[1];
    const int*   e_i2n   = (const int*)d_in[2];
    const int*   e_n2i   = (const int*)d_in[3];
    const float* W_src   = (const float*)d_in[4];
    const float* W_dst   = (const float*)d_in[5];
    const float* att_src = (const float*)d_in[6];
    const float* att_dst = (const float*)d_in[7];
    const float* bias_g  = (const float*)d_in[8];
    const float* lin1_w  = (const float*)d_in[9];
    const float* lin1_b  = (const float*)d_in[10];
    const float* lin2_w  = (const float*)d_in[11];
    const float* lin2_b  = (const float*)d_in[12];

    const int n_inst = in_sizes[0] / H;
    const int n_net  = in_sizes[1] / H;
    const int ne     = in_sizes[2] / 2;
    const int nmax   = n_inst > n_net ? n_inst : n_net;

    const int nbA = (n_net + BUCKET - 1) >> BSHIFT;
    const int nbB = (n_inst + BUCKET - 1) >> BSHIFT;
    const int nch = (ne + CHUNK - 1) / CHUNK;   // must be <= 512

    float* ws = (float*)d_ws;
    size_t off = 0;
    auto alloc = [&](size_t nelem) {
        off = (off + 3) & ~(size_t)3;
        float* p = ws + off; off += nelem; return p;
    };
    __half* xiA    = (__half*)alloc((size_t)n_inst * H / 2);
    __half* hs02   = (__half*)alloc((size_t)nmax * H);       // interleaved [N][64][2] fp16
    __half* hs1    = (__half*)alloc((size_t)nmax * H / 2);
    float* ssrc02  = alloc((size_t)nmax * 2);
    float* ssrc1   = alloc(nmax);
    float* sdstA   = alloc(nmax);
    float* sdstB   = alloc(nmax);
    int*   rp_i2n  = (int*)alloc(nmax + 1);
    int*   sr_i2n  = (int*)alloc(ne);
    int*   rp_n2i  = (int*)alloc(nmax + 1);
    int*   sr_n2i  = (int*)alloc(ne);
    unsigned* tmpA = (unsigned*)alloc(ne);
    unsigned* tmpB = (unsigned*)alloc(ne);
    int*   cntA    = (int*)alloc((size_t)NBMAX * nch);
    int*   cntB    = (int*)alloc((size_t)NBMAX * nch);
    int*   totA    = (int*)alloc(NBMAX);
    int*   totB    = (int*)alloc(NBMAX);
    int*   bstartA = (int*)alloc(NBMAX + 1);
    int*   bstartB = (int*)alloc(NBMAX + 1);
    float* v2all   = alloc(3 * H);
    (void)ws_size;

    const int* dstA = e_i2n + ne;   // dst = net
    const int* dstB = e_n2i + ne;   // dst = inst

    wvec3_kernel<<<3, 64, 0, stream>>>(W_dst, att_dst, v2all);

    // hist (A+B) || proj0 -> interleaved slot 0
    {
        int grid = 2 * nch + (n_inst + 15) / 16;
        hist_proj_kernel<<<grid, 256, 0, stream>>>(dstA, dstB, cntA, cntB, ne, nch, nbA, nbB,
                                                   x_inst, W_src + 0 * H * H, att_src + 0 * H,
                                                   v2all + 1 * H, hs02, ssrc02, sdstB, n_inst);
    }
    scan_chunks<<<nbA + nbB, 512, 0, stream>>>(cntA, cntB, totA, totB, nch, nbA);
    scan_buckets<<<2, 256, 0, stream>>>(totA, totB, bstartA, bstartB, nbA, nbB, ne);
    // scatter (A+B) || proj1
    {
        int grid = 2 * nch + (n_net + 15) / 16;
        scatter_proj_kernel<<<grid, 256, 0, stream>>>(e_i2n, dstA, cntA, bstartA, tmpA,
                                                      e_n2i, dstB, cntB, bstartB, tmpB,
                                                      ne, nch, nbA, nbB,
                                                      x_net, W_src + 1 * H * H, att_src + 1 * H,
                                                      v2all + 0 * H, hs1, ssrc1, sdstA, n_net);
    }
    bucket_finalize<<<nbA + nbB, 512, 0, stream>>>(tmpA, bstartA, rp_i2n, sr_i2n, n_net, nbA,
                                                   tmpB, bstartB, rp_n2i, sr_n2i, n_inst);

    // gat1 (rel1 -> fp16 xiA, 2 nodes/wave, bpermute broadcast)
    {
        int npair = (n_inst + 1) / 2;
        gat1_kernel<<<(npair + 3) / 4, 256, 0, stream>>>(rp_n2i, sr_n2i, ssrc1, sdstB,
                                                         hs1, bias_g + 1 * H, xiA, n_inst);
    }
    // proj2: fp16 xiA -> interleaved slot 1
    proj_half_kernel<<<(n_inst + 15) / 16, 256, 0, stream>>>(xiA, W_src + 2 * H * H,
                                                             att_src + 2 * H, hs02, ssrc02, n_inst);
    // fused gat0+gat2+MLP -> d_out
    gat02_mlp_kernel<<<(n_net + 3) / 4, 256, 0, stream>>>(rp_i2n, sr_i2n,
                                                          ssrc02, sdstA, hs02, bias_g + 0 * H,
                                                          v2all + 2 * H, bias_g + 2 * H,
                                                          lin1_w, lin1_b, lin2_w, lin2_b,
                                                          (float*)d_out, n_net);
}